// Round 2
// baseline (1093.216 us; speedup 1.0000x reference)
//
#include <hip/hip_runtime.h>
#include <hip/hip_bf16.h>

constexpr int N = 50000;
constexpr int E = 600000;
constexpr int D = 128;
constexpr int L = 2;

// scan chunking
constexpr int CH = 128;
constexpr int LOOK = 192;

// workspace layout (in floats).  hbuf aliases sums (sums dead after k_norm).
constexpr size_t OFF_SUMS = 0;                          // N*D   (phase A)
constexpr size_t OFF_H    = 0;                          // N*D   (phase B)
constexpr size_t OFF_CNT  = (size_t)N * D;              // N
constexpr size_t OFF_X    = OFF_CNT + N;                // N*D
constexpr size_t OFF_ZG   = OFF_X + (size_t)N * D;      // N*2D
// total: N*(128+1+128+256) floats = 102.6 MB

// ---------------------------------------------------------------------------
// Kernel 1: edge aggregation.  One wave (64 lanes) per edge, 2 dims per lane.
// ---------------------------------------------------------------------------
__global__ __launch_bounds__(256) void k_edge(
    const int* __restrict__ eidx, const int* __restrict__ etype,
    const int* __restrict__ etime, const float* __restrict__ ew,
    const float* __restrict__ ent, const float* __restrict__ rel,
    const float* __restrict__ tim,
    float* __restrict__ sums, float* __restrict__ cnt)
{
    int wave = threadIdx.x >> 6;
    int lane = threadIdx.x & 63;
    int e = blockIdx.x * 4 + wave;
    if (e >= E) return;

    int src = eidx[e];
    int dst = eidx[E + e];
    int rt  = etype[e];
    int tt  = etime[e];
    float w = ew[e];

    const float2 a = *(const float2*)(ent + (size_t)src * D + 2 * lane);
    const float2 b = *(const float2*)(rel + (size_t)rt  * D + 2 * lane);
    const float2 c = *(const float2*)(tim + (size_t)tt  * D + 2 * lane);

    float m0 = (a.x + b.x + c.x) * w;
    float m1 = (a.y + b.y + c.y) * w;

    float* p = sums + (size_t)dst * D + 2 * lane;
    atomicAdd(p,     m0);
    atomicAdd(p + 1, m1);
    if (lane == 0) atomicAdd(cnt + dst, w);
}

// ---------------------------------------------------------------------------
// Kernel 2: x = sums/max(cnt,1); row L2-normalize; apply perm (gather).
// Block i handles OUTPUT row i = input row perm[i].
// ---------------------------------------------------------------------------
__global__ __launch_bounds__(128) void k_norm(
    const float* __restrict__ sums, const float* __restrict__ cnt,
    const int* __restrict__ perm, float* __restrict__ xbuf)
{
    int i = blockIdx.x;
    int d = threadIdx.x;
    int r = perm[i];
    float inv = 1.0f / fmaxf(cnt[r], 1.0f);
    float v = sums[(size_t)r * D + d] * inv;

    float ss = v * v;
    #pragma unroll
    for (int m = 32; m >= 1; m >>= 1) ss += __shfl_xor(ss, m, 64);

    __shared__ float red[2];
    if ((threadIdx.x & 63) == 0) red[threadIdx.x >> 6] = ss;
    __syncthreads();
    float tot = red[0] + red[1];

    float scale = 1.0f / fmaxf(sqrtf(tot), 1e-12f);
    xbuf[(size_t)i * D + d] = v * scale;
}

// ---------------------------------------------------------------------------
// Kernel 3: zg = x @ Wi + bi   ([N,128] @ [128,256]).  8 rows per block.
// ---------------------------------------------------------------------------
__global__ __launch_bounds__(256) void k_inproj(
    const float* __restrict__ xbuf, const float* __restrict__ Wi,
    const float* __restrict__ bi, float* __restrict__ zg)
{
    __shared__ float xs[8][128];
    int row0 = blockIdx.x * 8;
    int c = threadIdx.x;

    for (int t = threadIdx.x; t < 8 * 128; t += 256)
        xs[t >> 7][t & 127] = xbuf[(size_t)row0 * 128 + t];
    __syncthreads();

    float bias = bi[c];
    float acc[8];
    #pragma unroll
    for (int r = 0; r < 8; r++) acc[r] = bias;

    #pragma unroll 4
    for (int k = 0; k < 128; k++) {
        float w = Wi[k * 256 + c];
        #pragma unroll
        for (int r = 0; r < 8; r++) acc[r] += xs[r][k] * w;
    }
    #pragma unroll
    for (int r = 0; r < 8; r++)
        zg[((size_t)row0 + r) * 256 + c] = acc[r];
}

// ---------------------------------------------------------------------------
// Kernel 4: chunked scan with redundant lookback.
// h_i = sigmoid(g_i) * (A*h_{i-1}) + B*z_i.  |g*A| < ~0.4 so 192-step
// lookback leaves truncation error < 1e-50 — no cross-chunk dependency.
// ---------------------------------------------------------------------------
__global__ __launch_bounds__(128) void k_scan(
    const float* __restrict__ zg, const float* __restrict__ Aw,
    const float* __restrict__ Bw, float* __restrict__ hbuf)
{
    int d = threadIdx.x;
    float Ad = Aw[d];
    float Bd = Bw[d];

    int start = blockIdx.x * CH;
    int lb = start - LOOK; if (lb < 0) lb = 0;
    int end = start + CH; if (end > N) end = N;

    float h = 0.0f;
    for (int i = lb; i < start; ++i) {
        float z  = zg[(size_t)i * 256 + d];
        float gv = zg[(size_t)i * 256 + 128 + d];
        float g = 1.0f / (1.0f + __expf(-gv));
        h = g * (Ad * h) + Bd * z;
    }
    for (int i = start; i < end; ++i) {
        float z  = zg[(size_t)i * 256 + d];
        float gv = zg[(size_t)i * 256 + 128 + d];
        float g = 1.0f / (1.0f + __expf(-gv));
        h = g * (Ad * h) + Bd * z;
        hbuf[(size_t)i * 128 + d] = h;
    }
}

// ---------------------------------------------------------------------------
// Kernel 5: y = x + h @ Wo + bo; LayerNorm.  8 rows per block.
// Writes fp32 to `xout` (in-place into xbuf is safe: each element is
// read+written by exactly one thread, read first).
// ---------------------------------------------------------------------------
__global__ __launch_bounds__(128) void k_outln(
    const float* __restrict__ xbuf, const float* __restrict__ hbuf,
    const float* __restrict__ Wo, const float* __restrict__ bo,
    const float* __restrict__ g_ln, const float* __restrict__ b_ln,
    float* __restrict__ xout)
{
    __shared__ float hs[8][128];
    int row0 = blockIdx.x * 8;
    int c = threadIdx.x;

    for (int t = threadIdx.x; t < 8 * 128; t += 128)
        hs[t >> 7][t & 127] = hbuf[(size_t)row0 * 128 + t];
    __syncthreads();

    float bias = bo[c];
    float acc[8];
    #pragma unroll
    for (int r = 0; r < 8; r++) acc[r] = bias;

    #pragma unroll 4
    for (int k = 0; k < 128; k++) {
        float w = Wo[k * 128 + c];
        #pragma unroll
        for (int r = 0; r < 8; r++) acc[r] += hs[r][k] * w;
    }

    float y[8], s[8], ss[8];
    #pragma unroll
    for (int r = 0; r < 8; r++) {
        y[r] = xbuf[((size_t)row0 + r) * 128 + c] + acc[r];
        s[r] = y[r];
        ss[r] = y[r] * y[r];
    }
    #pragma unroll
    for (int m = 32; m >= 1; m >>= 1) {
        #pragma unroll
        for (int r = 0; r < 8; r++) {
            s[r]  += __shfl_xor(s[r],  m, 64);
            ss[r] += __shfl_xor(ss[r], m, 64);
        }
    }
    __shared__ float red[2][2][8];
    int wv = threadIdx.x >> 6;
    if ((threadIdx.x & 63) == 0) {
        #pragma unroll
        for (int r = 0; r < 8; r++) { red[wv][0][r] = s[r]; red[wv][1][r] = ss[r]; }
    }
    __syncthreads();

    float gl = g_ln[c];
    float bl = b_ln[c];
    #pragma unroll
    for (int r = 0; r < 8; r++) {
        float sum = red[0][0][r] + red[1][0][r];
        float sq  = red[0][1][r] + red[1][1][r];
        float mu  = sum * (1.0f / 128.0f);
        float var = sq * (1.0f / 128.0f) - mu * mu;
        float o = (y[r] - mu) * rsqrtf(var + 1e-5f) * gl + bl;
        xout[((size_t)row0 + r) * 128 + c] = o;
    }
}

extern "C" void kernel_launch(void* const* d_in, const int* in_sizes, int n_in,
                              void* d_out, int out_size, void* d_ws, size_t ws_size,
                              hipStream_t stream)
{
    const int*   eidx  = (const int*)d_in[0];
    const int*   etype = (const int*)d_in[1];
    const int*   etime = (const int*)d_in[2];
    const float* ew    = (const float*)d_in[3];
    const int*   perm  = (const int*)d_in[4];
    const float* ent   = (const float*)d_in[5];
    const float* rel   = (const float*)d_in[6];
    const float* tim   = (const float*)d_in[7];
    const float* Wi    = (const float*)d_in[8];
    const float* bi    = (const float*)d_in[9];
    const float* Wo    = (const float*)d_in[10];
    const float* bo    = (const float*)d_in[11];
    const float* Aw    = (const float*)d_in[12];
    const float* Bw    = (const float*)d_in[13];
    const float* lg    = (const float*)d_in[14];
    const float* lbp   = (const float*)d_in[15];

    float* ws   = (float*)d_ws;
    float* sums = ws + OFF_SUMS;
    float* cnt  = ws + OFF_CNT;
    float* xbuf = ws + OFF_X;
    float* zg   = ws + OFF_ZG;
    float* hbuf = ws + OFF_H;   // aliases sums (dead after k_norm)

    // zero sums+cnt (contiguous region [0, N*D+N))
    hipMemsetAsync(sums, 0, ((size_t)N * D + N) * sizeof(float), stream);

    k_edge<<<E / 4, 256, 0, stream>>>(eidx, etype, etime, ew, ent, rel, tim,
                                      sums, cnt);
    k_norm<<<N, 128, 0, stream>>>(sums, cnt, perm, xbuf);

    float* outp = (float*)d_out;
    for (int l = 0; l < L; ++l) {
        k_inproj<<<N / 8, 256, 0, stream>>>(xbuf, Wi + (size_t)l * D * 2 * D,
                                            bi + (size_t)l * 2 * D, zg);
        k_scan<<<(N + CH - 1) / CH, 128, 0, stream>>>(zg, Aw + l * D, Bw + l * D,
                                                      hbuf);
        k_outln<<<N / 8, 128, 0, stream>>>(
            xbuf, hbuf, Wo + (size_t)l * D * D, bo + l * D,
            lg + l * D, lbp + l * D, (l == L - 1) ? outp : xbuf);
    }
}

// Round 3
// 593.960 us; speedup vs baseline: 1.8406x; 1.8406x over previous
//
#include <hip/hip_runtime.h>

constexpr int N = 50000;
constexpr int E = 600000;
constexpr int D = 128;
constexpr int L = 2;
constexpr int NB = (N + 255) / 256;   // 196 scan blocks

// scan chunking: decay per step <= ~max|A| ~= 0.35; 0.35^64 ~ 1e-29
constexpr int CH = 64;
constexpr int LOOK = 64;

// workspace layout (floats):
//   [0, N*D)        hbuf
//   [N*D, 2N*D)     xbuf
//   [2N*D, 2N*D+2N*D) zg   (sort scratch aliases this region pre-layer-loop)
constexpr size_t OFF_H  = 0;
constexpr size_t OFF_X  = (size_t)N * D;
constexpr size_t OFF_ZG = (size_t)2 * N * D;

// ---------------------------------------------------------------------------
// Sort pass 1: histogram of dst
// ---------------------------------------------------------------------------
__global__ __launch_bounds__(256) void k_hist(
    const int* __restrict__ dstp, int* __restrict__ hist)
{
    int e = blockIdx.x * 256 + threadIdx.x;
    if (e < E) atomicAdd(&hist[dstp[e]], 1);
}

// ---------------------------------------------------------------------------
// Sort pass 2a: per-256-chunk exclusive scan; chunk totals -> bsum
// ---------------------------------------------------------------------------
__global__ __launch_bounds__(256) void k_scan1(
    const int* __restrict__ hist, int* __restrict__ part, int* __restrict__ bsum)
{
    int i = blockIdx.x * 256 + threadIdx.x;
    int v = (i < N) ? hist[i] : 0;
    int lane = threadIdx.x & 63, wv = threadIdx.x >> 6;
    int s = v;
    #pragma unroll
    for (int m = 1; m < 64; m <<= 1) {
        int t = __shfl_up(s, m, 64);
        if (lane >= m) s += t;
    }
    __shared__ int wsum[4];
    if (lane == 63) wsum[wv] = s;
    __syncthreads();
    int off = 0;
    for (int w = 0; w < wv; w++) off += wsum[w];
    if (i < N) part[i] = s - v + off;
    if (threadIdx.x == 255)
        bsum[blockIdx.x] = wsum[0] + wsum[1] + wsum[2] + wsum[3];
}

// ---------------------------------------------------------------------------
// Sort pass 2b: exclusive scan of the NB (<=256) chunk totals, in place
// ---------------------------------------------------------------------------
__global__ __launch_bounds__(256) void k_scan2(int* __restrict__ bsum)
{
    int i = threadIdx.x;
    int v = (i < NB) ? bsum[i] : 0;
    int lane = i & 63, wv = i >> 6;
    int s = v;
    #pragma unroll
    for (int m = 1; m < 64; m <<= 1) {
        int t = __shfl_up(s, m, 64);
        if (lane >= m) s += t;
    }
    __shared__ int wsum[4];
    if (lane == 63) wsum[wv] = s;
    __syncthreads();
    int off = 0;
    for (int w = 0; w < wv; w++) off += wsum[w];
    if (i < NB) bsum[i] = s - v + off;
}

// ---------------------------------------------------------------------------
// Sort pass 2c: cursor/row_start = global exclusive prefix; also inverse perm
// ---------------------------------------------------------------------------
__global__ __launch_bounds__(256) void k_finalize(
    const int* __restrict__ part, const int* __restrict__ bsum,
    int* __restrict__ cursor, int* __restrict__ rowst,
    const int* __restrict__ perm, int* __restrict__ invp)
{
    int i = blockIdx.x * 256 + threadIdx.x;
    if (i < N) {
        int b = part[i] + bsum[i >> 8];
        cursor[i] = b;
        rowst[i] = b;
        invp[perm[i]] = i;
    }
}

// ---------------------------------------------------------------------------
// Sort pass 3: scatter packed edge records into dst-grouped order
// ---------------------------------------------------------------------------
__global__ __launch_bounds__(256) void k_scatter(
    const int* __restrict__ eidx, const int* __restrict__ etype,
    const int* __restrict__ etime, const float* __restrict__ ew,
    int* __restrict__ cursor, int4* __restrict__ esort)
{
    int e = blockIdx.x * 256 + threadIdx.x;
    if (e >= E) return;
    int dst = eidx[E + e];
    int slot = atomicAdd(&cursor[dst], 1);
    int4 p;
    p.x = eidx[e];
    p.y = etype[e];
    p.z = etime[e];
    p.w = __float_as_int(ew[e]);
    esort[slot] = p;
}

// ---------------------------------------------------------------------------
// Aggregation: one wave per dst row.  Atomic-free.  Fuses scatter-mean,
// row L2-normalize, and the perm gather (via inverse perm) -> writes xbuf.
// ---------------------------------------------------------------------------
__global__ __launch_bounds__(256) void k_agg(
    const int4* __restrict__ esort, const int* __restrict__ rowst,
    const int* __restrict__ hist, const int* __restrict__ invp,
    const float* __restrict__ ent, const float* __restrict__ rel,
    const float* __restrict__ tim, float* __restrict__ xbuf)
{
    int wv = threadIdx.x >> 6, lane = threadIdx.x & 63;
    int d = blockIdx.x * 4 + wv;
    if (d >= N) return;
    int beg = rowst[d];
    int n = hist[d];

    float a0 = 0.f, a1 = 0.f, wsum = 0.f;
    for (int j = 0; j < n; ++j) {
        int4 p = esort[beg + j];
        float w = __int_as_float(p.w);
        float2 va = *(const float2*)(ent + (size_t)p.x * D + 2 * lane);
        float2 vb = *(const float2*)(rel + (size_t)p.y * D + 2 * lane);
        float2 vc = *(const float2*)(tim + (size_t)p.z * D + 2 * lane);
        a0 += (va.x + vb.x + vc.x) * w;
        a1 += (va.y + vb.y + vc.y) * w;
        wsum += w;
    }
    float inv = 1.0f / fmaxf(wsum, 1.0f);
    a0 *= inv; a1 *= inv;

    float ss = a0 * a0 + a1 * a1;
    #pragma unroll
    for (int m = 32; m >= 1; m >>= 1) ss += __shfl_xor(ss, m, 64);
    float sc = 1.0f / fmaxf(sqrtf(ss), 1e-12f);

    int orow = invp[d];
    *(float2*)(xbuf + (size_t)orow * D + 2 * lane) =
        make_float2(a0 * sc, a1 * sc);
}

// ---------------------------------------------------------------------------
// zg = x @ Wi + bi   ([N,128] @ [128,256]).  8 rows per block.
// ---------------------------------------------------------------------------
__global__ __launch_bounds__(256) void k_inproj(
    const float* __restrict__ xbuf, const float* __restrict__ Wi,
    const float* __restrict__ bi, float* __restrict__ zg)
{
    __shared__ float xs[8][128];
    int row0 = blockIdx.x * 8;
    int c = threadIdx.x;

    for (int t = threadIdx.x; t < 8 * 128; t += 256)
        xs[t >> 7][t & 127] = xbuf[(size_t)row0 * 128 + t];
    __syncthreads();

    float bias = bi[c];
    float acc[8];
    #pragma unroll
    for (int r = 0; r < 8; r++) acc[r] = bias;

    #pragma unroll 4
    for (int k = 0; k < 128; k++) {
        float w = Wi[k * 256 + c];
        #pragma unroll
        for (int r = 0; r < 8; r++) acc[r] += xs[r][k] * w;
    }
    #pragma unroll
    for (int r = 0; r < 8; r++)
        zg[((size_t)row0 + r) * 256 + c] = acc[r];
}

// ---------------------------------------------------------------------------
// Chunked scan with redundant lookback.
// ---------------------------------------------------------------------------
__global__ __launch_bounds__(128) void k_scan(
    const float* __restrict__ zg, const float* __restrict__ Aw,
    const float* __restrict__ Bw, float* __restrict__ hbuf)
{
    int d = threadIdx.x;
    float Ad = Aw[d];
    float Bd = Bw[d];

    int start = blockIdx.x * CH;
    int lb = start - LOOK; if (lb < 0) lb = 0;
    int end = start + CH; if (end > N) end = N;

    float h = 0.0f;
    for (int i = lb; i < start; ++i) {
        float z  = zg[(size_t)i * 256 + d];
        float gv = zg[(size_t)i * 256 + 128 + d];
        float g = 1.0f / (1.0f + __expf(-gv));
        h = g * (Ad * h) + Bd * z;
    }
    for (int i = start; i < end; ++i) {
        float z  = zg[(size_t)i * 256 + d];
        float gv = zg[(size_t)i * 256 + 128 + d];
        float g = 1.0f / (1.0f + __expf(-gv));
        h = g * (Ad * h) + Bd * z;
        hbuf[(size_t)i * 128 + d] = h;
    }
}

// ---------------------------------------------------------------------------
// y = x + h @ Wo + bo; LayerNorm.  8 rows per block.
// ---------------------------------------------------------------------------
__global__ __launch_bounds__(128) void k_outln(
    const float* __restrict__ xbuf, const float* __restrict__ hbuf,
    const float* __restrict__ Wo, const float* __restrict__ bo,
    const float* __restrict__ g_ln, const float* __restrict__ b_ln,
    float* __restrict__ xout)
{
    __shared__ float hs[8][128];
    int row0 = blockIdx.x * 8;
    int c = threadIdx.x;

    for (int t = threadIdx.x; t < 8 * 128; t += 128)
        hs[t >> 7][t & 127] = hbuf[(size_t)row0 * 128 + t];
    __syncthreads();

    float bias = bo[c];
    float acc[8];
    #pragma unroll
    for (int r = 0; r < 8; r++) acc[r] = bias;

    #pragma unroll 4
    for (int k = 0; k < 128; k++) {
        float w = Wo[k * 128 + c];
        #pragma unroll
        for (int r = 0; r < 8; r++) acc[r] += hs[r][k] * w;
    }

    float y[8], s[8], ss[8];
    #pragma unroll
    for (int r = 0; r < 8; r++) {
        y[r] = xbuf[((size_t)row0 + r) * 128 + c] + acc[r];
        s[r] = y[r];
        ss[r] = y[r] * y[r];
    }
    #pragma unroll
    for (int m = 32; m >= 1; m >>= 1) {
        #pragma unroll
        for (int r = 0; r < 8; r++) {
            s[r]  += __shfl_xor(s[r],  m, 64);
            ss[r] += __shfl_xor(ss[r], m, 64);
        }
    }
    __shared__ float red[2][2][8];
    int wv = threadIdx.x >> 6;
    if ((threadIdx.x & 63) == 0) {
        #pragma unroll
        for (int r = 0; r < 8; r++) { red[wv][0][r] = s[r]; red[wv][1][r] = ss[r]; }
    }
    __syncthreads();

    float gl = g_ln[c];
    float bl = b_ln[c];
    #pragma unroll
    for (int r = 0; r < 8; r++) {
        float sum = red[0][0][r] + red[1][0][r];
        float sq  = red[0][1][r] + red[1][1][r];
        float mu  = sum * (1.0f / 128.0f);
        float var = sq * (1.0f / 128.0f) - mu * mu;
        float o = (y[r] - mu) * rsqrtf(var + 1e-5f) * gl + bl;
        xout[((size_t)row0 + r) * 128 + c] = o;
    }
}

extern "C" void kernel_launch(void* const* d_in, const int* in_sizes, int n_in,
                              void* d_out, int out_size, void* d_ws, size_t ws_size,
                              hipStream_t stream)
{
    const int*   eidx  = (const int*)d_in[0];
    const int*   etype = (const int*)d_in[1];
    const int*   etime = (const int*)d_in[2];
    const float* ew    = (const float*)d_in[3];
    const int*   perm  = (const int*)d_in[4];
    const float* ent   = (const float*)d_in[5];
    const float* rel   = (const float*)d_in[6];
    const float* tim   = (const float*)d_in[7];
    const float* Wi    = (const float*)d_in[8];
    const float* bi    = (const float*)d_in[9];
    const float* Wo    = (const float*)d_in[10];
    const float* bo    = (const float*)d_in[11];
    const float* Aw    = (const float*)d_in[12];
    const float* Bw    = (const float*)d_in[13];
    const float* lg    = (const float*)d_in[14];
    const float* lbp   = (const float*)d_in[15];

    float* ws   = (float*)d_ws;
    float* hbuf = ws + OFF_H;
    float* xbuf = ws + OFF_X;
    float* zg   = ws + OFF_ZG;

    // sort scratch aliases the zg region (dead until the layer loop)
    int*  ibase  = (int*)zg;
    int4* esort  = (int4*)ibase;        // E int4
    int*  hist   = ibase + (size_t)4 * E;
    int*  part   = hist + N;
    int*  bsum   = part + N;
    int*  cursor = bsum + 256;
    int*  rowst  = cursor + N;
    int*  invp   = rowst + N;

    hipMemsetAsync(hist, 0, N * sizeof(int), stream);

    k_hist    <<<(E + 255) / 256, 256, 0, stream>>>(eidx + E, hist);
    k_scan1   <<<NB, 256, 0, stream>>>(hist, part, bsum);
    k_scan2   <<<1, 256, 0, stream>>>(bsum);
    k_finalize<<<NB, 256, 0, stream>>>(part, bsum, cursor, rowst, perm, invp);
    k_scatter <<<(E + 255) / 256, 256, 0, stream>>>(eidx, etype, etime, ew,
                                                    cursor, esort);
    k_agg     <<<(N + 3) / 4, 256, 0, stream>>>(esort, rowst, hist, invp,
                                                ent, rel, tim, xbuf);

    float* outp = (float*)d_out;
    for (int l = 0; l < L; ++l) {
        k_inproj<<<N / 8, 256, 0, stream>>>(xbuf, Wi + (size_t)l * D * 2 * D,
                                            bi + (size_t)l * 2 * D, zg);
        k_scan<<<(N + CH - 1) / CH, 128, 0, stream>>>(zg, Aw + l * D, Bw + l * D,
                                                      hbuf);
        k_outln<<<N / 8, 128, 0, stream>>>(
            xbuf, hbuf, Wo + (size_t)l * D * D, bo + l * D,
            lg + l * D, lbp + l * D, (l == L - 1) ? outp : xbuf);
    }
}

// Round 4
// 397.438 us; speedup vs baseline: 2.7507x; 1.4945x over previous
//
#include <hip/hip_runtime.h>
#include <hip/hip_bf16.h>

typedef __attribute__((ext_vector_type(8))) short bf8;
typedef __attribute__((ext_vector_type(4))) float f32x4;

constexpr int N = 50000;
constexpr int E = 600000;
constexpr int D = 128;
constexpr int L = 2;
constexpr int NB = (N + 255) / 256;

// scan chunking: decay/step <= max|A| ~ 0.35; 0.35^32 ~ 2e-15
constexpr int CH = 32;
constexpr int LOOK = 32;

__device__ __forceinline__ float b2f(__hip_bfloat16 v) { return __bfloat162float(v); }

// ---------------------------------------------------------------------------
// Sort pass 1: histogram of dst
// ---------------------------------------------------------------------------
__global__ __launch_bounds__(256) void k_hist(
    const int* __restrict__ dstp, int* __restrict__ hist)
{
    int e = blockIdx.x * 256 + threadIdx.x;
    if (e < E) atomicAdd(&hist[dstp[e]], 1);
}

__global__ __launch_bounds__(256) void k_scan1(
    const int* __restrict__ hist, int* __restrict__ part, int* __restrict__ bsum)
{
    int i = blockIdx.x * 256 + threadIdx.x;
    int v = (i < N) ? hist[i] : 0;
    int lane = threadIdx.x & 63, wv = threadIdx.x >> 6;
    int s = v;
    #pragma unroll
    for (int m = 1; m < 64; m <<= 1) {
        int t = __shfl_up(s, m, 64);
        if (lane >= m) s += t;
    }
    __shared__ int wsum[4];
    if (lane == 63) wsum[wv] = s;
    __syncthreads();
    int off = 0;
    for (int w = 0; w < wv; w++) off += wsum[w];
    if (i < N) part[i] = s - v + off;
    if (threadIdx.x == 255)
        bsum[blockIdx.x] = wsum[0] + wsum[1] + wsum[2] + wsum[3];
}

__global__ __launch_bounds__(256) void k_scan2(int* __restrict__ bsum)
{
    int i = threadIdx.x;
    int v = (i < NB) ? bsum[i] : 0;
    int lane = i & 63, wv = i >> 6;
    int s = v;
    #pragma unroll
    for (int m = 1; m < 64; m <<= 1) {
        int t = __shfl_up(s, m, 64);
        if (lane >= m) s += t;
    }
    __shared__ int wsum[4];
    if (lane == 63) wsum[wv] = s;
    __syncthreads();
    int off = 0;
    for (int w = 0; w < wv; w++) off += wsum[w];
    if (i < NB) bsum[i] = s - v + off;
}

__global__ __launch_bounds__(256) void k_finalize(
    const int* __restrict__ part, const int* __restrict__ bsum,
    int* __restrict__ cursor, int* __restrict__ rowst,
    const int* __restrict__ perm, int* __restrict__ invp)
{
    int i = blockIdx.x * 256 + threadIdx.x;
    if (i < N) {
        int b = part[i] + bsum[i >> 8];
        cursor[i] = b;
        rowst[i] = b;
        invp[perm[i]] = i;
    }
}

__global__ __launch_bounds__(256) void k_scatter(
    const int* __restrict__ eidx, const int* __restrict__ etype,
    const int* __restrict__ etime, const float* __restrict__ ew,
    int* __restrict__ cursor, int4* __restrict__ esort)
{
    int e = blockIdx.x * 256 + threadIdx.x;
    if (e >= E) return;
    int dst = eidx[E + e];
    int slot = atomicAdd(&cursor[dst], 1);
    int4 p;
    p.x = eidx[e];
    p.y = etype[e];
    p.z = etime[e];
    p.w = __float_as_int(ew[e]);
    esort[slot] = p;
}

// ---------------------------------------------------------------------------
// Weight cast: WiT[l][256][128], WoT[l][128][128] bf16 (pre-transposed)
// ---------------------------------------------------------------------------
__global__ __launch_bounds__(256) void k_castw(
    const float* __restrict__ Wi, const float* __restrict__ Wo,
    __hip_bfloat16* __restrict__ WiT, __hip_bfloat16* __restrict__ WoT)
{
    int t = blockIdx.x * 256 + threadIdx.x;
    if (t < L * 256 * 128) {
        int l = t / (256 * 128), r = t % (256 * 128);
        int n = r / 128, k = r % 128;
        WiT[t] = __float2bfloat16(Wi[(size_t)l * 128 * 256 + k * 256 + n]);
    } else if (t < L * 256 * 128 + L * 128 * 128) {
        int u = t - L * 256 * 128;
        int l = u / (128 * 128), r = u % (128 * 128);
        int n = r / 128, k = r % 128;
        WoT[u] = __float2bfloat16(Wo[(size_t)l * 128 * 128 + k * 128 + n]);
    }
}

// ---------------------------------------------------------------------------
// Aggregation: one wave per dst row, unrolled by 2.  Fuses scatter-mean,
// L2-normalize, perm gather.  Writes xbuf (fp32) and xbf (bf16).
// ---------------------------------------------------------------------------
__global__ __launch_bounds__(256) void k_agg(
    const int4* __restrict__ esort, const int* __restrict__ rowst,
    const int* __restrict__ hist, const int* __restrict__ invp,
    const float* __restrict__ ent, const float* __restrict__ rel,
    const float* __restrict__ tim, float* __restrict__ xbuf,
    __hip_bfloat16* __restrict__ xbf)
{
    int wv = threadIdx.x >> 6, lane = threadIdx.x & 63;
    int d = blockIdx.x * 4 + wv;
    if (d >= N) return;
    int beg = rowst[d];
    int n = hist[d];

    float a0 = 0.f, a1 = 0.f, b0 = 0.f, b1 = 0.f, ws0 = 0.f, ws1 = 0.f;
    int j = 0;
    for (; j + 1 < n; j += 2) {
        int4 p = esort[beg + j];
        int4 q = esort[beg + j + 1];
        float wp = __int_as_float(p.w);
        float wq = __int_as_float(q.w);
        float2 pa = *(const float2*)(ent + (size_t)p.x * D + 2 * lane);
        float2 qa = *(const float2*)(ent + (size_t)q.x * D + 2 * lane);
        float2 pb = *(const float2*)(rel + (size_t)p.y * D + 2 * lane);
        float2 qb = *(const float2*)(rel + (size_t)q.y * D + 2 * lane);
        float2 pc = *(const float2*)(tim + (size_t)p.z * D + 2 * lane);
        float2 qc = *(const float2*)(tim + (size_t)q.z * D + 2 * lane);
        a0 += (pa.x + pb.x + pc.x) * wp;
        a1 += (pa.y + pb.y + pc.y) * wp;
        b0 += (qa.x + qb.x + qc.x) * wq;
        b1 += (qa.y + qb.y + qc.y) * wq;
        ws0 += wp; ws1 += wq;
    }
    if (j < n) {
        int4 p = esort[beg + j];
        float wp = __int_as_float(p.w);
        float2 pa = *(const float2*)(ent + (size_t)p.x * D + 2 * lane);
        float2 pb = *(const float2*)(rel + (size_t)p.y * D + 2 * lane);
        float2 pc = *(const float2*)(tim + (size_t)p.z * D + 2 * lane);
        a0 += (pa.x + pb.x + pc.x) * wp;
        a1 += (pa.y + pb.y + pc.y) * wp;
        ws0 += wp;
    }
    a0 += b0; a1 += b1;
    float wsum = ws0 + ws1;

    float inv = 1.0f / fmaxf(wsum, 1.0f);
    a0 *= inv; a1 *= inv;

    float ss = a0 * a0 + a1 * a1;
    #pragma unroll
    for (int m = 32; m >= 1; m >>= 1) ss += __shfl_xor(ss, m, 64);
    float sc = 1.0f / fmaxf(sqrtf(ss), 1e-12f);
    float v0 = a0 * sc, v1 = a1 * sc;

    int orow = invp[d];
    *(float2*)(xbuf + (size_t)orow * D + 2 * lane) = make_float2(v0, v1);
    __hip_bfloat162 hb;
    hb.x = __float2bfloat16(v0);
    hb.y = __float2bfloat16(v1);
    *(__hip_bfloat162*)(xbf + (size_t)orow * D + 2 * lane) = hb;
}

// ---------------------------------------------------------------------------
// in_proj via MFMA: zg[N,256] = x[N,128] @ Wi[128,256] + bi, bf16 in/out.
// Block = 16 rows x 256 cols; wave w covers 64 cols.
// ---------------------------------------------------------------------------
__global__ __launch_bounds__(256) void k_inproj(
    const __hip_bfloat16* __restrict__ xbf, const __hip_bfloat16* __restrict__ WiT,
    const float* __restrict__ bi, __hip_bfloat16* __restrict__ zgb)
{
    int tid = threadIdx.x;
    int w = tid >> 6, lane = tid & 63;
    int quad = lane >> 4, m = lane & 15;
    int r0 = blockIdx.x * 16;
    int cb = w * 64;

    const short* xp = (const short*)xbf;
    bf8 a[4];
    #pragma unroll
    for (int kb = 0; kb < 4; kb++)
        a[kb] = *(const bf8*)(xp + (size_t)(r0 + m) * 128 + kb * 32 + quad * 8);

    f32x4 zero = {0.f, 0.f, 0.f, 0.f};
    f32x4 acc[4] = {zero, zero, zero, zero};
    const short* wp = (const short*)WiT;
    #pragma unroll
    for (int sub = 0; sub < 4; sub++) {
        int col = cb + sub * 16 + m;
        #pragma unroll
        for (int kb = 0; kb < 4; kb++) {
            bf8 b = *(const bf8*)(wp + (size_t)col * 128 + kb * 32 + quad * 8);
            acc[sub] = __builtin_amdgcn_mfma_f32_16x16x32_bf16(a[kb], b, acc[sub], 0, 0, 0);
        }
    }
    #pragma unroll
    for (int sub = 0; sub < 4; sub++) {
        int col = cb + sub * 16 + m;
        float bias = bi[col];
        #pragma unroll
        for (int reg = 0; reg < 4; reg++) {
            int row = r0 + quad * 4 + reg;
            zgb[(size_t)row * 256 + col] = __float2bfloat16(acc[sub][reg] + bias);
        }
    }
}

// ---------------------------------------------------------------------------
// Chunked scan with redundant lookback (bf16 in, bf16 out)
// ---------------------------------------------------------------------------
__global__ __launch_bounds__(128) void k_scan(
    const __hip_bfloat16* __restrict__ zgb, const float* __restrict__ Aw,
    const float* __restrict__ Bw, __hip_bfloat16* __restrict__ hbf)
{
    int d = threadIdx.x;
    float Ad = Aw[d];
    float Bd = Bw[d];

    int start = blockIdx.x * CH;
    int lb = start - LOOK; if (lb < 0) lb = 0;
    int end = start + CH; if (end > N) end = N;

    float h = 0.0f;
    #pragma unroll 4
    for (int i = lb; i < start; ++i) {
        float z  = b2f(zgb[(size_t)i * 256 + d]);
        float gv = b2f(zgb[(size_t)i * 256 + 128 + d]);
        float g = 1.0f / (1.0f + __expf(-gv));
        h = g * (Ad * h) + Bd * z;
    }
    #pragma unroll 4
    for (int i = start; i < end; ++i) {
        float z  = b2f(zgb[(size_t)i * 256 + d]);
        float gv = b2f(zgb[(size_t)i * 256 + 128 + d]);
        float g = 1.0f / (1.0f + __expf(-gv));
        h = g * (Ad * h) + Bd * z;
        hbf[(size_t)i * 128 + d] = __float2bfloat16(h);
    }
}

// ---------------------------------------------------------------------------
// out_proj + residual + LayerNorm via MFMA.  Block = 16 rows x 128 cols;
// wave w covers 32 cols.  Writes fp32 xout (+ bf16 xbfout if non-null).
// ---------------------------------------------------------------------------
__global__ __launch_bounds__(256) void k_outln(
    const float* __restrict__ xbuf, const __hip_bfloat16* __restrict__ hbf,
    const __hip_bfloat16* __restrict__ WoT, const float* __restrict__ bo,
    const float* __restrict__ lg, const float* __restrict__ lb,
    float* __restrict__ xout, __hip_bfloat16* __restrict__ xbfout)
{
    __shared__ float yl[16][129];
    __shared__ float mu_s[16], rs_s[16];

    int tid = threadIdx.x;
    int w = tid >> 6, lane = tid & 63;
    int quad = lane >> 4, m = lane & 15;
    int r0 = blockIdx.x * 16;
    int cb = w * 32;

    const short* hp = (const short*)hbf;
    bf8 a[4];
    #pragma unroll
    for (int kb = 0; kb < 4; kb++)
        a[kb] = *(const bf8*)(hp + (size_t)(r0 + m) * 128 + kb * 32 + quad * 8);

    f32x4 zero = {0.f, 0.f, 0.f, 0.f};
    f32x4 acc[2] = {zero, zero};
    const short* wp = (const short*)WoT;
    #pragma unroll
    for (int sub = 0; sub < 2; sub++) {
        int col = cb + sub * 16 + m;
        #pragma unroll
        for (int kb = 0; kb < 4; kb++) {
            bf8 b = *(const bf8*)(wp + (size_t)col * 128 + kb * 32 + quad * 8);
            acc[sub] = __builtin_amdgcn_mfma_f32_16x16x32_bf16(a[kb], b, acc[sub], 0, 0, 0);
        }
    }
    #pragma unroll
    for (int sub = 0; sub < 2; sub++) {
        int col = cb + sub * 16 + m;
        float bias = bo[col];
        #pragma unroll
        for (int reg = 0; reg < 4; reg++) {
            int lr = quad * 4 + reg;
            yl[lr][col] = acc[sub][reg] + bias + xbuf[(size_t)(r0 + lr) * 128 + col];
        }
    }
    __syncthreads();

    if (tid < 128) {
        int row = tid >> 3, part = tid & 7;
        float s = 0.f, ss = 0.f;
        #pragma unroll
        for (int i = 0; i < 16; i++) {
            float v = yl[row][part * 16 + i];
            s += v; ss += v * v;
        }
        s  += __shfl_xor(s, 1, 64);  ss += __shfl_xor(ss, 1, 64);
        s  += __shfl_xor(s, 2, 64);  ss += __shfl_xor(ss, 2, 64);
        s  += __shfl_xor(s, 4, 64);  ss += __shfl_xor(ss, 4, 64);
        if (part == 0) {
            float mu = s * (1.0f / 128.0f);
            float var = ss * (1.0f / 128.0f) - mu * mu;
            mu_s[row] = mu;
            rs_s[row] = rsqrtf(var + 1e-5f);
        }
    }
    __syncthreads();

    int col = tid & 127;
    float gl = lg[col], bl = lb[col];
    #pragma unroll
    for (int i = 0; i < 8; i++) {
        int flat = i * 256 + tid;
        int row = flat >> 7;
        float v = (yl[row][col] - mu_s[row]) * rs_s[row] * gl + bl;
        xout[(size_t)(r0 + row) * 128 + col] = v;
        if (xbfout)
            xbfout[(size_t)(r0 + row) * 128 + col] = __float2bfloat16(v);
    }
}

extern "C" void kernel_launch(void* const* d_in, const int* in_sizes, int n_in,
                              void* d_out, int out_size, void* d_ws, size_t ws_size,
                              hipStream_t stream)
{
    const int*   eidx  = (const int*)d_in[0];
    const int*   etype = (const int*)d_in[1];
    const int*   etime = (const int*)d_in[2];
    const float* ew    = (const float*)d_in[3];
    const int*   perm  = (const int*)d_in[4];
    const float* ent   = (const float*)d_in[5];
    const float* rel   = (const float*)d_in[6];
    const float* tim   = (const float*)d_in[7];
    const float* Wi    = (const float*)d_in[8];
    const float* bi    = (const float*)d_in[9];
    const float* Wo    = (const float*)d_in[10];
    const float* bo    = (const float*)d_in[11];
    const float* Aw    = (const float*)d_in[12];
    const float* Bw    = (const float*)d_in[13];
    const float* lg    = (const float*)d_in[14];
    const float* lbp   = (const float*)d_in[15];

    // workspace layout (bytes)
    char* base = (char*)d_ws;
    float*           xbuf = (float*)base;                                   // 25.6 MB
    __hip_bfloat16*  xbf  = (__hip_bfloat16*)(base + (size_t)N * D * 4);    // 12.8 MB
    __hip_bfloat16*  zgb  = (__hip_bfloat16*)(base + (size_t)N * D * 6);    // 25.6 MB
    __hip_bfloat16*  hbf  = (__hip_bfloat16*)(base + (size_t)N * D * 10);   // 12.8 MB
    __hip_bfloat16*  WiT  = (__hip_bfloat16*)(base + (size_t)N * D * 12);   // 128 KB
    __hip_bfloat16*  WoT  = WiT + (size_t)L * 256 * 128;                    // 64 KB

    // sort scratch aliases the zgb region (dead until the layer loop)
    int*  ibase  = (int*)zgb;
    int4* esort  = (int4*)ibase;            // E int4 = 9.6 MB
    int*  hist   = ibase + (size_t)4 * E;
    int*  part   = hist + N;
    int*  bsum   = part + N;
    int*  cursor = bsum + 256;
    int*  rowst  = cursor + N;
    int*  invp   = rowst + N;

    hipMemsetAsync(hist, 0, N * sizeof(int), stream);

    k_castw   <<<(L * 256 * 128 + L * 128 * 128 + 255) / 256, 256, 0, stream>>>(
                Wi, Wo, WiT, WoT);
    k_hist    <<<(E + 255) / 256, 256, 0, stream>>>(eidx + E, hist);
    k_scan1   <<<NB, 256, 0, stream>>>(hist, part, bsum);
    k_scan2   <<<1, 256, 0, stream>>>(bsum);
    k_finalize<<<NB, 256, 0, stream>>>(part, bsum, cursor, rowst, perm, invp);
    k_scatter <<<(E + 255) / 256, 256, 0, stream>>>(eidx, etype, etime, ew,
                                                    cursor, esort);
    k_agg     <<<(N + 3) / 4, 256, 0, stream>>>(esort, rowst, hist, invp,
                                                ent, rel, tim, xbuf, xbf);

    float* outp = (float*)d_out;
    for (int l = 0; l < L; ++l) {
        k_inproj<<<N / 16, 256, 0, stream>>>(xbf, WiT + (size_t)l * 256 * 128,
                                             bi + (size_t)l * 256, zgb);
        k_scan<<<(N + CH - 1) / CH, 128, 0, stream>>>(zgb, Aw + l * D, Bw + l * D,
                                                      hbf);
        k_outln<<<N / 16, 256, 0, stream>>>(
            xbuf, hbf, WoT + (size_t)l * 128 * 128, bo + l * D,
            lg + l * D, lbp + l * D,
            (l == L - 1) ? outp : xbuf,
            (l == L - 1) ? nullptr : xbf);
    }
}

// Round 5
// 345.444 us; speedup vs baseline: 3.1647x; 1.1505x over previous
//
#include <hip/hip_runtime.h>
#include <hip/hip_bf16.h>

typedef unsigned short ushort_t;
typedef unsigned int   uint_t;
typedef __attribute__((ext_vector_type(8))) short bf8;
typedef __attribute__((ext_vector_type(4))) float f32x4;

constexpr int N = 50000;
constexpr int E = 600000;
constexpr int D = 128;
constexpr int L = 2;
constexpr int NB = (N + 255) / 256;

// fused layer tiling: 64 output rows/block + 16 lookback rows
constexpr int TR   = 64;
constexpr int LOOK = 16;
constexpr int RT   = TR + LOOK;          // 80
constexpr int NBLK = (N + TR - 1) / TR;  // 782

// LDS layout inside k_layer (bytes):
//  zs  [128][82] u16  @ 0        (20992)   col-major z
//  gs  [128][82] u16  @ 20992    (20992)   col-major sigmoid(g)
//  hs  [64][136] u16  @ 41984    (17408)   row-major h (136 = 16B-aligned rows)
//  red float[128]     @ 59392    (512)     mu[64], rsig[64]
//  ys  [64][132] f32  @ 0        (33792)   aliases zs/gs (dead after scan)
constexpr int SM_ZS  = 0;
constexpr int SM_GS  = 20992;
constexpr int SM_HS  = 41984;
constexpr int SM_RED = 59392;
constexpr int SM_TOT = 59904;

__device__ __forceinline__ float us2f(ushort_t u) {
    union { uint_t i; float f; } c; c.i = (uint_t)u << 16; return c.f;
}
__device__ __forceinline__ ushort_t f2us(float f) {
    __hip_bfloat16 b = __float2bfloat16(f);
    return *(ushort_t*)&b;
}

// ---------------------------------------------------------------------------
// Sorting passes (dst-grouped edge records)
// ---------------------------------------------------------------------------
__global__ __launch_bounds__(256) void k_hist(
    const int* __restrict__ dstp, int* __restrict__ hist)
{
    int e = blockIdx.x * 256 + threadIdx.x;
    if (e < E) atomicAdd(&hist[dstp[e]], 1);
}

__global__ __launch_bounds__(256) void k_scan1(
    const int* __restrict__ hist, int* __restrict__ part, int* __restrict__ bsum)
{
    int i = blockIdx.x * 256 + threadIdx.x;
    int v = (i < N) ? hist[i] : 0;
    int lane = threadIdx.x & 63, wv = threadIdx.x >> 6;
    int s = v;
    #pragma unroll
    for (int m = 1; m < 64; m <<= 1) {
        int t = __shfl_up(s, m, 64);
        if (lane >= m) s += t;
    }
    __shared__ int wsum[4];
    if (lane == 63) wsum[wv] = s;
    __syncthreads();
    int off = 0;
    for (int w = 0; w < wv; w++) off += wsum[w];
    if (i < N) part[i] = s - v + off;
    if (threadIdx.x == 255)
        bsum[blockIdx.x] = wsum[0] + wsum[1] + wsum[2] + wsum[3];
}

__global__ __launch_bounds__(256) void k_scan2(int* __restrict__ bsum)
{
    int i = threadIdx.x;
    int v = (i < NB) ? bsum[i] : 0;
    int lane = i & 63, wv = i >> 6;
    int s = v;
    #pragma unroll
    for (int m = 1; m < 64; m <<= 1) {
        int t = __shfl_up(s, m, 64);
        if (lane >= m) s += t;
    }
    __shared__ int wsum[4];
    if (lane == 63) wsum[wv] = s;
    __syncthreads();
    int off = 0;
    for (int w = 0; w < wv; w++) off += wsum[w];
    if (i < NB) bsum[i] = s - v + off;
}

__global__ __launch_bounds__(256) void k_finalize(
    const int* __restrict__ part, const int* __restrict__ bsum,
    int* __restrict__ cursor, int* __restrict__ rowst,
    const int* __restrict__ perm, int* __restrict__ invp)
{
    int i = blockIdx.x * 256 + threadIdx.x;
    if (i < N) {
        int b = part[i] + bsum[i >> 8];
        cursor[i] = b;
        rowst[i] = b;
        invp[perm[i]] = i;
    }
}

// packed record: x = src | (type<<16); y = time | (w_bf16<<16)
__global__ __launch_bounds__(256) void k_scatter(
    const int* __restrict__ eidx, const int* __restrict__ etype,
    const int* __restrict__ etime, const float* __restrict__ ew,
    int* __restrict__ cursor, int2* __restrict__ esort)
{
    int e = blockIdx.x * 256 + threadIdx.x;
    if (e >= E) return;
    int dst = eidx[E + e];
    int slot = atomicAdd(&cursor[dst], 1);
    int2 p;
    p.x = (eidx[e] & 0xffff) | (etype[e] << 16);
    p.y = (etime[e] & 0xffff) | ((int)f2us(ew[e]) << 16);
    esort[slot] = p;
}

// ---------------------------------------------------------------------------
// Casts: tables (ent/rel/tim) fp32 -> bf16, two elems per thread
// ---------------------------------------------------------------------------
__global__ __launch_bounds__(256) void k_ctab(
    const float* __restrict__ ent, const float* __restrict__ rel,
    const float* __restrict__ tim, ushort_t* __restrict__ entb,
    ushort_t* __restrict__ relb, ushort_t* __restrict__ timb)
{
    size_t t = (size_t)blockIdx.x * 256 + threadIdx.x;
    const float2* s; uint_t* d; size_t off;
    if (t < 3200000)        { s = (const float2*)ent; d = (uint_t*)entb; off = t; }
    else if (t < 3212800)   { s = (const float2*)rel; d = (uint_t*)relb; off = t - 3200000; }
    else if (t < 3276800)   { s = (const float2*)tim; d = (uint_t*)timb; off = t - 3212800; }
    else return;
    float2 v = s[off];
    d[off] = (uint_t)f2us(v.x) | ((uint_t)f2us(v.y) << 16);
}

// weights: WiT[l][256][128], WoT[l][128][128] bf16 pre-transposed
__global__ __launch_bounds__(256) void k_castw(
    const float* __restrict__ Wi, const float* __restrict__ Wo,
    ushort_t* __restrict__ WiT, ushort_t* __restrict__ WoT)
{
    int t = blockIdx.x * 256 + threadIdx.x;
    if (t < L * 256 * 128) {
        int l = t / (256 * 128), r = t % (256 * 128);
        int n = r / 128, k = r % 128;
        WiT[t] = f2us(Wi[(size_t)l * 128 * 256 + k * 256 + n]);
    } else if (t < L * 256 * 128 + L * 128 * 128) {
        int u = t - L * 256 * 128;
        int l = u / (128 * 128), r = u % (128 * 128);
        int n = r / 128, k = r % 128;
        WoT[u] = f2us(Wo[(size_t)l * 128 * 128 + k * 128 + n]);
    }
}

// ---------------------------------------------------------------------------
// Aggregation: one wave per dst row; bf16 tables; packed records; unroll 2.
// Fuses scatter-mean, L2-normalize, perm gather.  Writes xbf (bf16).
// ---------------------------------------------------------------------------
__global__ __launch_bounds__(256) void k_agg(
    const int2* __restrict__ esort, const int* __restrict__ rowst,
    const int* __restrict__ hist, const int* __restrict__ invp,
    const ushort_t* __restrict__ entb, const ushort_t* __restrict__ relb,
    const ushort_t* __restrict__ timb, ushort_t* __restrict__ xbf)
{
    int wv = threadIdx.x >> 6, lane = threadIdx.x & 63;
    int d = blockIdx.x * 4 + wv;
    if (d >= N) return;
    int beg = rowst[d];
    int n = hist[d];

    float a0 = 0.f, a1 = 0.f, b0 = 0.f, b1 = 0.f, ws0 = 0.f, ws1 = 0.f;
    int j = 0;
    for (; j + 1 < n; j += 2) {
        int2 p = esort[beg + j];
        int2 q = esort[beg + j + 1];
        int  ps = p.x & 0xffff, pt = ((uint_t)p.x) >> 16;
        int  qs = q.x & 0xffff, qt = ((uint_t)q.x) >> 16;
        int  pm = p.y & 0xffff, qm = q.y & 0xffff;
        float wp = us2f((ushort_t)(((uint_t)p.y) >> 16));
        float wq = us2f((ushort_t)(((uint_t)q.y) >> 16));
        uint_t pa = *(const uint_t*)(entb + (size_t)ps * D + 2 * lane);
        uint_t qa = *(const uint_t*)(entb + (size_t)qs * D + 2 * lane);
        uint_t pb = *(const uint_t*)(relb + (size_t)pt * D + 2 * lane);
        uint_t qb = *(const uint_t*)(relb + (size_t)qt * D + 2 * lane);
        uint_t pc = *(const uint_t*)(timb + (size_t)pm * D + 2 * lane);
        uint_t qc = *(const uint_t*)(timb + (size_t)qm * D + 2 * lane);
        a0 += (us2f(pa & 0xffff) + us2f(pb & 0xffff) + us2f(pc & 0xffff)) * wp;
        a1 += (us2f(pa >> 16)    + us2f(pb >> 16)    + us2f(pc >> 16))    * wp;
        b0 += (us2f(qa & 0xffff) + us2f(qb & 0xffff) + us2f(qc & 0xffff)) * wq;
        b1 += (us2f(qa >> 16)    + us2f(qb >> 16)    + us2f(qc >> 16))    * wq;
        ws0 += wp; ws1 += wq;
    }
    if (j < n) {
        int2 p = esort[beg + j];
        int  ps = p.x & 0xffff, pt = ((uint_t)p.x) >> 16;
        int  pm = p.y & 0xffff;
        float wp = us2f((ushort_t)(((uint_t)p.y) >> 16));
        uint_t pa = *(const uint_t*)(entb + (size_t)ps * D + 2 * lane);
        uint_t pb = *(const uint_t*)(relb + (size_t)pt * D + 2 * lane);
        uint_t pc = *(const uint_t*)(timb + (size_t)pm * D + 2 * lane);
        a0 += (us2f(pa & 0xffff) + us2f(pb & 0xffff) + us2f(pc & 0xffff)) * wp;
        a1 += (us2f(pa >> 16)    + us2f(pb >> 16)    + us2f(pc >> 16))    * wp;
        ws0 += wp;
    }
    a0 += b0; a1 += b1;
    float inv = 1.0f / fmaxf(ws0 + ws1, 1.0f);
    a0 *= inv; a1 *= inv;

    float ss = a0 * a0 + a1 * a1;
    #pragma unroll
    for (int m = 32; m >= 1; m >>= 1) ss += __shfl_xor(ss, m, 64);
    float sc = 1.0f / fmaxf(sqrtf(ss), 1e-12f);

    int orow = invp[d];
    uint_t out = (uint_t)f2us(a0 * sc) | ((uint_t)f2us(a1 * sc) << 16);
    *(uint_t*)(xbf + (size_t)orow * D + 2 * lane) = out;
}

// ---------------------------------------------------------------------------
// Fused mamba layer: in_proj MFMA -> LDS -> scan -> out_proj MFMA -> LN.
// Block = 64 output rows (+16 lookback).  256 threads = 4 waves.
// ---------------------------------------------------------------------------
template <bool FINAL>
__global__ __launch_bounds__(256, 2) void k_layer(
    const ushort_t* __restrict__ xin, const ushort_t* __restrict__ WiT,
    const float* __restrict__ bi, const ushort_t* __restrict__ WoT,
    const float* __restrict__ bo, const float* __restrict__ Aw,
    const float* __restrict__ Bw, const float* __restrict__ lg,
    const float* __restrict__ lb, ushort_t* __restrict__ xoutb,
    float* __restrict__ outf)
{
    __shared__ char sm[SM_TOT];
    ushort_t* zs  = (ushort_t*)(sm + SM_ZS);    // [128][82]
    ushort_t* gs  = (ushort_t*)(sm + SM_GS);    // [128][82]
    ushort_t* hs  = (ushort_t*)(sm + SM_HS);    // [64][136]
    float*    red = (float*)(sm + SM_RED);      // mu[64], rsig[64]
    float*    ys  = (float*)sm;                 // [64][132], aliases zs/gs

    int tid = threadIdx.x;
    int w = tid >> 6, lane = tid & 63;
    int quad = lane >> 4, m = lane & 15;
    int r0 = blockIdx.x * TR;
    int base = r0 - LOOK;

    const bf8 zero8 = {0, 0, 0, 0, 0, 0, 0, 0};
    const f32x4 zero4 = {0.f, 0.f, 0.f, 0.f};

    // ---- phase 1: zg = x @ Wi + bi for rows [base, base+80) ----
    {
        int cb = w * 64;
        bf8 bfrag[4][4];
        #pragma unroll
        for (int sub = 0; sub < 4; sub++)
            #pragma unroll
            for (int kb = 0; kb < 4; kb++)
                bfrag[sub][kb] = *(const bf8*)(WiT + (size_t)(cb + sub * 16 + m) * 128
                                               + kb * 32 + quad * 8);
        #pragma unroll
        for (int rt = 0; rt < 5; rt++) {
            int gr = base + rt * 16 + m;
            bf8 a[4];
            if (gr >= 0 && gr < N) {
                #pragma unroll
                for (int kb = 0; kb < 4; kb++)
                    a[kb] = *(const bf8*)(xin + (size_t)gr * 128 + kb * 32 + quad * 8);
            } else {
                #pragma unroll
                for (int kb = 0; kb < 4; kb++) a[kb] = zero8;
            }
            f32x4 acc[4] = {zero4, zero4, zero4, zero4};
            #pragma unroll
            for (int sub = 0; sub < 4; sub++)
                #pragma unroll
                for (int kb = 0; kb < 4; kb++)
                    acc[sub] = __builtin_amdgcn_mfma_f32_16x16x32_bf16(
                        a[kb], bfrag[sub][kb], acc[sub], 0, 0, 0);
            #pragma unroll
            for (int sub = 0; sub < 4; sub++) {
                int col = cb + sub * 16 + m;
                float bias = bi[col];
                #pragma unroll
                for (int reg = 0; reg < 4; reg++) {
                    int rr = rt * 16 + quad * 4 + reg;
                    float v = acc[sub][reg] + bias;
                    if (col < 128)
                        zs[col * 82 + rr] = f2us(v);
                    else
                        gs[(col - 128) * 82 + rr] = f2us(1.f / (1.f + __expf(-v)));
                }
            }
        }
    }
    __syncthreads();

    // ---- phase 2: sequential scan over 80 rows (threads 0..127, 1/dim) ----
    if (tid < 128) {
        int dd = tid;
        float Ad = Aw[dd], Bd = Bw[dd], h = 0.f;
        int rrs = (base < 0) ? LOOK : 0;
        int lim = N - base; if (lim > RT) lim = RT;
        for (int rr = rrs; rr < lim; ++rr) {
            float z = us2f(zs[dd * 82 + rr]);
            float g = us2f(gs[dd * 82 + rr]);
            h = g * (Ad * h) + Bd * z;
            if (rr >= LOOK) hs[(rr - LOOK) * 136 + dd] = f2us(h);
        }
    }
    __syncthreads();

    // ---- phase 3: y = x + h @ Wo + bo  (writes ys, aliasing zs/gs) ----
    {
        int cb = w * 32;
        bf8 b2[2][4];
        #pragma unroll
        for (int sub = 0; sub < 2; sub++)
            #pragma unroll
            for (int kb = 0; kb < 4; kb++)
                b2[sub][kb] = *(const bf8*)(WoT + (size_t)(cb + sub * 16 + m) * 128
                                            + kb * 32 + quad * 8);
        #pragma unroll
        for (int rt = 0; rt < 4; rt++) {
            bf8 a[4];
            #pragma unroll
            for (int kb = 0; kb < 4; kb++)
                a[kb] = *(const bf8*)(hs + (rt * 16 + m) * 136 + kb * 32 + quad * 8);
            f32x4 acc[2] = {zero4, zero4};
            #pragma unroll
            for (int sub = 0; sub < 2; sub++)
                #pragma unroll
                for (int kb = 0; kb < 4; kb++)
                    acc[sub] = __builtin_amdgcn_mfma_f32_16x16x32_bf16(
                        a[kb], b2[sub][kb], acc[sub], 0, 0, 0);
            #pragma unroll
            for (int sub = 0; sub < 2; sub++) {
                int col = cb + sub * 16 + m;
                float bias = bo[col];
                #pragma unroll
                for (int reg = 0; reg < 4; reg++) {
                    int rr = rt * 16 + quad * 4 + reg;
                    int gr = r0 + rr;
                    float res = (gr < N) ? us2f(xin[(size_t)gr * 128 + col]) : 0.f;
                    ys[rr * 132 + col] = acc[sub][reg] + bias + res;
                }
            }
        }
    }
    __syncthreads();

    // ---- phase 4: LayerNorm ----
    {
        int row = tid >> 2, part = tid & 3;
        float s = 0.f, ss = 0.f;
        #pragma unroll
        for (int i = 0; i < 32; i++) {
            float v = ys[row * 132 + part * 32 + i];
            s += v; ss += v * v;
        }
        s += __shfl_xor(s, 1, 64); ss += __shfl_xor(ss, 1, 64);
        s += __shfl_xor(s, 2, 64); ss += __shfl_xor(ss, 2, 64);
        if (part == 0) {
            float mu = s * (1.f / 128.f);
            float var = ss * (1.f / 128.f) - mu * mu;
            red[row] = mu;
            red[64 + row] = rsqrtf(var + 1e-5f);
        }
    }
    __syncthreads();

    #pragma unroll
    for (int i = 0; i < 32; i++) {
        int flat = i * 256 + tid;
        int rr = flat >> 7, col = flat & 127;
        int gr = r0 + rr;
        if (gr < N) {
            float v = (ys[rr * 132 + col] - red[rr]) * red[64 + rr] * lg[col] + lb[col];
            if (FINAL) outf[(size_t)gr * 128 + col] = v;
            else       xoutb[(size_t)gr * 128 + col] = f2us(v);
        }
    }
}

extern "C" void kernel_launch(void* const* d_in, const int* in_sizes, int n_in,
                              void* d_out, int out_size, void* d_ws, size_t ws_size,
                              hipStream_t stream)
{
    const int*   eidx  = (const int*)d_in[0];
    const int*   etype = (const int*)d_in[1];
    const int*   etime = (const int*)d_in[2];
    const float* ew    = (const float*)d_in[3];
    const int*   perm  = (const int*)d_in[4];
    const float* ent   = (const float*)d_in[5];
    const float* rel   = (const float*)d_in[6];
    const float* tim   = (const float*)d_in[7];
    const float* Wi    = (const float*)d_in[8];
    const float* bi    = (const float*)d_in[9];
    const float* Wo    = (const float*)d_in[10];
    const float* bo    = (const float*)d_in[11];
    const float* Aw    = (const float*)d_in[12];
    const float* Bw    = (const float*)d_in[13];
    const float* lg    = (const float*)d_in[14];
    const float* lbp   = (const float*)d_in[15];

    char* base = (char*)d_ws;
    size_t o = 0;
    ushort_t* xbf  = (ushort_t*)(base + o); o += (size_t)N * D * 2;       // 12.8 MB
    ushort_t* xb2  = (ushort_t*)(base + o); o += (size_t)N * D * 2;       // 12.8 MB
    ushort_t* entb = (ushort_t*)(base + o); o += (size_t)N * D * 2;       // 12.8 MB
    ushort_t* relb = (ushort_t*)(base + o); o += (size_t)200 * D * 2;
    ushort_t* timb = (ushort_t*)(base + o); o += (size_t)1000 * D * 2;
    ushort_t* WiT  = (ushort_t*)(base + o); o += (size_t)L * 256 * 128 * 2;
    ushort_t* WoT  = (ushort_t*)(base + o); o += (size_t)L * 128 * 128 * 2;
    int2*     esort  = (int2*)(base + o);   o += (size_t)E * 8;           // 4.8 MB
    int*      hist   = (int*)(base + o);    o += (size_t)N * 4;
    int*      part   = (int*)(base + o);    o += (size_t)N * 4;
    int*      bsum   = (int*)(base + o);    o += 256 * 4;
    int*      cursor = (int*)(base + o);    o += (size_t)N * 4;
    int*      rowst  = (int*)(base + o);    o += (size_t)N * 4;
    int*      invp   = (int*)(base + o);    o += (size_t)N * 4;

    hipMemsetAsync(hist, 0, N * sizeof(int), stream);

    k_ctab    <<<12800, 256, 0, stream>>>(ent, rel, tim, entb, relb, timb);
    k_castw   <<<(L * 256 * 128 + L * 128 * 128 + 255) / 256, 256, 0, stream>>>(
                Wi, Wo, WiT, WoT);
    k_hist    <<<(E + 255) / 256, 256, 0, stream>>>(eidx + E, hist);
    k_scan1   <<<NB, 256, 0, stream>>>(hist, part, bsum);
    k_scan2   <<<1, 256, 0, stream>>>(bsum);
    k_finalize<<<NB, 256, 0, stream>>>(part, bsum, cursor, rowst, perm, invp);
    k_scatter <<<(E + 255) / 256, 256, 0, stream>>>(eidx, etype, etime, ew,
                                                    cursor, esort);
    k_agg     <<<(N + 3) / 4, 256, 0, stream>>>(esort, rowst, hist, invp,
                                                entb, relb, timb, xbf);

    k_layer<false><<<NBLK, 256, 0, stream>>>(
        xbf, WiT, bi, WoT, bo, Aw, Bw, lg, lbp, xb2, nullptr);
    k_layer<true><<<NBLK, 256, 0, stream>>>(
        xb2, WiT + (size_t)256 * 128, bi + 256, WoT + (size_t)128 * 128,
        bo + 128, Aw + 128, Bw + 128, lg + 128, lbp + 128,
        nullptr, (float*)d_out);
}

// Round 6
// 330.403 us; speedup vs baseline: 3.3087x; 1.0455x over previous
//
#include <hip/hip_runtime.h>
#include <hip/hip_bf16.h>

typedef unsigned short ushort_t;
typedef unsigned int   uint_t;
typedef __attribute__((ext_vector_type(8))) short bf8;
typedef __attribute__((ext_vector_type(4))) float f32x4;

constexpr int N = 50000;
constexpr int E = 600000;
constexpr int D = 128;
constexpr int L = 2;
constexpr int NB = (N + 255) / 256;

// fused layer tiling: 48 output rows/block + 16 lookback (decay 0.35^16 ~ 5e-8)
constexpr int TR   = 48;
constexpr int LOOK = 16;
constexpr int RT   = TR + LOOK;          // 64
constexpr int NBLK = (N + TR - 1) / TR;  // 1042
constexpr int SD   = 67;                 // zgp column stride (dwords); bank=(3d+rr)%32

__device__ __forceinline__ float us2f(ushort_t u) {
    union { uint_t i; float f; } c; c.i = (uint_t)u << 16; return c.f;
}
__device__ __forceinline__ ushort_t f2us(float f) {
    __hip_bfloat16 b = __float2bfloat16(f);
    return *(ushort_t*)&b;
}

// ---------------------------------------------------------------------------
// Sorting passes (dst-grouped edge records)
// ---------------------------------------------------------------------------
__global__ __launch_bounds__(256) void k_hist(
    const int* __restrict__ dstp, int* __restrict__ hist)
{
    int e = blockIdx.x * 256 + threadIdx.x;
    if (e < E) atomicAdd(&hist[dstp[e]], 1);
}

__global__ __launch_bounds__(256) void k_scan1(
    const int* __restrict__ hist, int* __restrict__ part, int* __restrict__ bsum)
{
    int i = blockIdx.x * 256 + threadIdx.x;
    int v = (i < N) ? hist[i] : 0;
    int lane = threadIdx.x & 63, wv = threadIdx.x >> 6;
    int s = v;
    #pragma unroll
    for (int m = 1; m < 64; m <<= 1) {
        int t = __shfl_up(s, m, 64);
        if (lane >= m) s += t;
    }
    __shared__ int wsum[4];
    if (lane == 63) wsum[wv] = s;
    __syncthreads();
    int off = 0;
    for (int w = 0; w < wv; w++) off += wsum[w];
    if (i < N) part[i] = s - v + off;
    if (threadIdx.x == 255)
        bsum[blockIdx.x] = wsum[0] + wsum[1] + wsum[2] + wsum[3];
}

__global__ __launch_bounds__(256) void k_scan2(int* __restrict__ bsum)
{
    int i = threadIdx.x;
    int v = (i < NB) ? bsum[i] : 0;
    int lane = i & 63, wv = i >> 6;
    int s = v;
    #pragma unroll
    for (int m = 1; m < 64; m <<= 1) {
        int t = __shfl_up(s, m, 64);
        if (lane >= m) s += t;
    }
    __shared__ int wsum[4];
    if (lane == 63) wsum[wv] = s;
    __syncthreads();
    int off = 0;
    for (int w = 0; w < wv; w++) off += wsum[w];
    if (i < NB) bsum[i] = s - v + off;
}

__global__ __launch_bounds__(256) void k_finalize(
    const int* __restrict__ part, const int* __restrict__ bsum,
    int* __restrict__ cursor, int* __restrict__ rowst,
    const int* __restrict__ perm, int* __restrict__ invp)
{
    int i = blockIdx.x * 256 + threadIdx.x;
    if (i < N) {
        int b = part[i] + bsum[i >> 8];
        cursor[i] = b;
        rowst[i] = b;
        invp[perm[i]] = i;
    }
}

// packed record: x = src | (type<<16); y = time | (w_bf16<<16)
__global__ __launch_bounds__(256) void k_scatter(
    const int* __restrict__ eidx, const int* __restrict__ etype,
    const int* __restrict__ etime, const float* __restrict__ ew,
    int* __restrict__ cursor, int2* __restrict__ esort)
{
    int e = blockIdx.x * 256 + threadIdx.x;
    if (e >= E) return;
    int dst = eidx[E + e];
    int slot = atomicAdd(&cursor[dst], 1);
    int2 p;
    p.x = (eidx[e] & 0xffff) | (etype[e] << 16);
    p.y = (etime[e] & 0xffff) | ((int)f2us(ew[e]) << 16);
    esort[slot] = p;
}

// ---------------------------------------------------------------------------
// Casts: tables (ent/rel/tim) fp32 -> bf16
// ---------------------------------------------------------------------------
__global__ __launch_bounds__(256) void k_ctab(
    const float* __restrict__ ent, const float* __restrict__ rel,
    const float* __restrict__ tim, ushort_t* __restrict__ entb,
    ushort_t* __restrict__ relb, ushort_t* __restrict__ timb)
{
    size_t t = (size_t)blockIdx.x * 256 + threadIdx.x;
    const float2* s; uint_t* d; size_t off;
    if (t < 3200000)        { s = (const float2*)ent; d = (uint_t*)entb; off = t; }
    else if (t < 3212800)   { s = (const float2*)rel; d = (uint_t*)relb; off = t - 3200000; }
    else if (t < 3276800)   { s = (const float2*)tim; d = (uint_t*)timb; off = t - 3212800; }
    else return;
    float2 v = s[off];
    d[off] = (uint_t)f2us(v.x) | ((uint_t)f2us(v.y) << 16);
}

// weights: WiT[l][256][128], WoT[l][128][128] bf16 pre-transposed
__global__ __launch_bounds__(256) void k_castw(
    const float* __restrict__ Wi, const float* __restrict__ Wo,
    ushort_t* __restrict__ WiT, ushort_t* __restrict__ WoT)
{
    int t = blockIdx.x * 256 + threadIdx.x;
    if (t < L * 256 * 128) {
        int l = t / (256 * 128), r = t % (256 * 128);
        int n = r / 128, k = r % 128;
        WiT[t] = f2us(Wi[(size_t)l * 128 * 256 + k * 256 + n]);
    } else if (t < L * 256 * 128 + L * 128 * 128) {
        int u = t - L * 256 * 128;
        int l = u / (128 * 128), r = u % (128 * 128);
        int n = r / 128, k = r % 128;
        WoT[u] = f2us(Wo[(size_t)l * 128 * 128 + k * 128 + n]);
    }
}

// ---------------------------------------------------------------------------
// Aggregation: one wave per dst row; bf16 tables; packed records; unroll 2.
// ---------------------------------------------------------------------------
__global__ __launch_bounds__(256) void k_agg(
    const int2* __restrict__ esort, const int* __restrict__ rowst,
    const int* __restrict__ hist, const int* __restrict__ invp,
    const ushort_t* __restrict__ entb, const ushort_t* __restrict__ relb,
    const ushort_t* __restrict__ timb, ushort_t* __restrict__ xbf)
{
    int wv = threadIdx.x >> 6, lane = threadIdx.x & 63;
    int d = blockIdx.x * 4 + wv;
    if (d >= N) return;
    int beg = rowst[d];
    int n = hist[d];

    float a0 = 0.f, a1 = 0.f, b0 = 0.f, b1 = 0.f, ws0 = 0.f, ws1 = 0.f;
    int j = 0;
    for (; j + 1 < n; j += 2) {
        int2 p = esort[beg + j];
        int2 q = esort[beg + j + 1];
        int  ps = p.x & 0xffff, pt = ((uint_t)p.x) >> 16;
        int  qs = q.x & 0xffff, qt = ((uint_t)q.x) >> 16;
        int  pm = p.y & 0xffff, qm = q.y & 0xffff;
        float wp = us2f((ushort_t)(((uint_t)p.y) >> 16));
        float wq = us2f((ushort_t)(((uint_t)q.y) >> 16));
        uint_t pa = *(const uint_t*)(entb + (size_t)ps * D + 2 * lane);
        uint_t qa = *(const uint_t*)(entb + (size_t)qs * D + 2 * lane);
        uint_t pb = *(const uint_t*)(relb + (size_t)pt * D + 2 * lane);
        uint_t qb = *(const uint_t*)(relb + (size_t)qt * D + 2 * lane);
        uint_t pc = *(const uint_t*)(timb + (size_t)pm * D + 2 * lane);
        uint_t qc = *(const uint_t*)(timb + (size_t)qm * D + 2 * lane);
        a0 += (us2f(pa & 0xffff) + us2f(pb & 0xffff) + us2f(pc & 0xffff)) * wp;
        a1 += (us2f(pa >> 16)    + us2f(pb >> 16)    + us2f(pc >> 16))    * wp;
        b0 += (us2f(qa & 0xffff) + us2f(qb & 0xffff) + us2f(qc & 0xffff)) * wq;
        b1 += (us2f(qa >> 16)    + us2f(qb >> 16)    + us2f(qc >> 16))    * wq;
        ws0 += wp; ws1 += wq;
    }
    if (j < n) {
        int2 p = esort[beg + j];
        int  ps = p.x & 0xffff, pt = ((uint_t)p.x) >> 16;
        int  pm = p.y & 0xffff;
        float wp = us2f((ushort_t)(((uint_t)p.y) >> 16));
        uint_t pa = *(const uint_t*)(entb + (size_t)ps * D + 2 * lane);
        uint_t pb = *(const uint_t*)(relb + (size_t)pt * D + 2 * lane);
        uint_t pc = *(const uint_t*)(timb + (size_t)pm * D + 2 * lane);
        a0 += (us2f(pa & 0xffff) + us2f(pb & 0xffff) + us2f(pc & 0xffff)) * wp;
        a1 += (us2f(pa >> 16)    + us2f(pb >> 16)    + us2f(pc >> 16))    * wp;
        ws0 += wp;
    }
    a0 += b0; a1 += b1;
    float inv = 1.0f / fmaxf(ws0 + ws1, 1.0f);
    a0 *= inv; a1 *= inv;

    float ss = a0 * a0 + a1 * a1;
    #pragma unroll
    for (int m = 32; m >= 1; m >>= 1) ss += __shfl_xor(ss, m, 64);
    float sc = 1.0f / fmaxf(sqrtf(ss), 1e-12f);

    int orow = invp[d];
    uint_t out = (uint_t)f2us(a0 * sc) | ((uint_t)f2us(a1 * sc) << 16);
    *(uint_t*)(xbf + (size_t)orow * D + 2 * lane) = out;
}

// ---------------------------------------------------------------------------
// Fused mamba layer v2.  Block = 48 output rows (+16 lookback), 256 threads.
// LDS: zgp[128][67] uint (z lo | sig(g) hi), h written in-place into z slot.
// LN reduction scratch aliases zgp.  34.3 KB -> 4 blocks/CU.
// ---------------------------------------------------------------------------
template <bool FINAL>
__global__ __launch_bounds__(256, 4) void k_layer(
    const ushort_t* __restrict__ xin, const ushort_t* __restrict__ WiT,
    const float* __restrict__ bi, const ushort_t* __restrict__ WoT,
    const float* __restrict__ bo, const float* __restrict__ Aw,
    const float* __restrict__ Bw, const float* __restrict__ lg,
    const float* __restrict__ lb, ushort_t* __restrict__ xoutb,
    float* __restrict__ outf)
{
    __shared__ uint_t zgp[128 * SD];
    ushort_t* zg16 = (ushort_t*)zgp;
    float*    redS = (float*)zgp;        // [48][4]  (aliases zgp, post-barrier)
    float*    redQ = redS + 192;         // [48][4]
    float*    muA  = redS + 384;         // [48]
    float*    rsA  = redS + 432;         // [48]

    int tid = threadIdx.x;
    int w = tid >> 6, lane = tid & 63;
    int quad = lane >> 4, m = lane & 15;
    int r0 = blockIdx.x * TR;
    int base = r0 - LOOK;

    const bf8 zero8 = {0, 0, 0, 0, 0, 0, 0, 0};
    const f32x4 zero4 = {0.f, 0.f, 0.f, 0.f};

    // ---- phase 1: zg rows [base, base+64) ----
    {
        int cb = w * 64;
        #pragma unroll
        for (int sp = 0; sp < 2; sp++) {
            int c0 = cb + sp * 32 + m, c1 = c0 + 16;
            float bias0 = bi[c0], bias1 = bi[c1];
            bf8 b0[4], b1[4];
            #pragma unroll
            for (int kb = 0; kb < 4; kb++) {
                b0[kb] = *(const bf8*)(WiT + (size_t)c0 * 128 + kb * 32 + quad * 8);
                b1[kb] = *(const bf8*)(WiT + (size_t)c1 * 128 + kb * 32 + quad * 8);
            }
            #pragma unroll
            for (int rt = 0; rt < 4; rt++) {
                int gr = base + rt * 16 + m;
                bf8 a[4];
                if (gr >= 0 && gr < N) {
                    #pragma unroll
                    for (int kb = 0; kb < 4; kb++)
                        a[kb] = *(const bf8*)(xin + (size_t)gr * 128 + kb * 32 + quad * 8);
                } else {
                    #pragma unroll
                    for (int kb = 0; kb < 4; kb++) a[kb] = zero8;
                }
                f32x4 acc0 = zero4, acc1 = zero4;
                #pragma unroll
                for (int kb = 0; kb < 4; kb++) {
                    acc0 = __builtin_amdgcn_mfma_f32_16x16x32_bf16(a[kb], b0[kb], acc0, 0, 0, 0);
                    acc1 = __builtin_amdgcn_mfma_f32_16x16x32_bf16(a[kb], b1[kb], acc1, 0, 0, 0);
                }
                #pragma unroll
                for (int reg = 0; reg < 4; reg++) {
                    int rr = rt * 16 + quad * 4 + reg;
                    float v0 = acc0[reg] + bias0;
                    float v1 = acc1[reg] + bias1;
                    if (c0 < 128) {
                        zg16[(c0 * SD + rr) * 2] = f2us(v0);
                        zg16[(c1 * SD + rr) * 2] = f2us(v1);
                    } else {
                        zg16[((c0 - 128) * SD + rr) * 2 + 1] =
                            f2us(1.f / (1.f + __expf(-v0)));
                        zg16[((c1 - 128) * SD + rr) * 2 + 1] =
                            f2us(1.f / (1.f + __expf(-v1)));
                    }
                }
            }
        }
    }
    __syncthreads();

    // ---- phase 2: serial scan per dim (threads 0..127); h -> z slot ----
    if (tid < 128) {
        int d = tid;
        const uint_t* col = zgp + d * SD;
        ushort_t* hcol = (ushort_t*)col;
        float Ad = Aw[d], Bd = Bw[d], h = 0.f;
        if (base >= 0 && base + RT <= N) {
            #pragma unroll
            for (int b8 = 0; b8 < 8; b8++) {
                uint_t v[8];
                #pragma unroll
                for (int k = 0; k < 8; k++) v[k] = col[b8 * 8 + k];
                #pragma unroll
                for (int k = 0; k < 8; k++) {
                    int rr = b8 * 8 + k;
                    float z = us2f((ushort_t)(v[k] & 0xffff));
                    float g = us2f((ushort_t)(v[k] >> 16));
                    h = g * (Ad * h) + Bd * z;
                    if (rr >= LOOK) hcol[rr * 2] = f2us(h);
                }
            }
        } else {
            int s = (base < 0) ? LOOK : 0;
            int lim = N - base; if (lim > RT) lim = RT;
            for (int rr = s; rr < lim; rr++) {
                uint_t v = col[rr];
                float z = us2f((ushort_t)(v & 0xffff));
                float g = us2f((ushort_t)(v >> 16));
                h = g * (Ad * h) + Bd * z;
                if (rr >= LOOK) hcol[rr * 2] = f2us(h);
            }
        }
    }
    __syncthreads();

    // ---- phase 3: y = x + h @ Wo + bo  (y stays in registers) ----
    float y[3][2][4];
    {
        int cb = w * 32;
        int c0 = cb + m, c1 = c0 + 16;
        float bias0 = bo[c0], bias1 = bo[c1];
        bf8 b0[4], b1[4];
        #pragma unroll
        for (int kb = 0; kb < 4; kb++) {
            b0[kb] = *(const bf8*)(WoT + (size_t)c0 * 128 + kb * 32 + quad * 8);
            b1[kb] = *(const bf8*)(WoT + (size_t)c1 * 128 + kb * 32 + quad * 8);
        }
        #pragma unroll
        for (int rt = 0; rt < 3; rt++) {
            int hrow = rt * 16 + m + LOOK;
            bf8 a[4];
            #pragma unroll
            for (int kb = 0; kb < 4; kb++) {
                #pragma unroll
                for (int j = 0; j < 8; j++)
                    a[kb][j] = (short)zg16[((kb * 32 + quad * 8 + j) * SD + hrow) * 2];
            }
            f32x4 acc0 = zero4, acc1 = zero4;
            #pragma unroll
            for (int kb = 0; kb < 4; kb++) {
                acc0 = __builtin_amdgcn_mfma_f32_16x16x32_bf16(a[kb], b0[kb], acc0, 0, 0, 0);
                acc1 = __builtin_amdgcn_mfma_f32_16x16x32_bf16(a[kb], b1[kb], acc1, 0, 0, 0);
            }
            #pragma unroll
            for (int reg = 0; reg < 4; reg++) {
                int gr = r0 + rt * 16 + quad * 4 + reg;
                float r0v = 0.f, r1v = 0.f;
                if (gr < N) {
                    r0v = us2f(xin[(size_t)gr * 128 + c0]);
                    r1v = us2f(xin[(size_t)gr * 128 + c1]);
                }
                y[rt][0][reg] = acc0[reg] + bias0 + r0v;
                y[rt][1][reg] = acc1[reg] + bias1 + r1v;
            }
        }
    }
    __syncthreads();   // zgp dead; red arrays may now alias it

    // ---- phase 4: LayerNorm (register shuffle + small LDS combine) ----
    {
        float ps[3][4], pq[3][4];
        #pragma unroll
        for (int rt = 0; rt < 3; rt++)
            #pragma unroll
            for (int reg = 0; reg < 4; reg++) {
                float v0 = y[rt][0][reg], v1 = y[rt][1][reg];
                float s = v0 + v1, q = v0 * v0 + v1 * v1;
                #pragma unroll
                for (int mk = 1; mk <= 8; mk <<= 1) {
                    s += __shfl_xor(s, mk, 64);
                    q += __shfl_xor(q, mk, 64);
                }
                ps[rt][reg] = s; pq[rt][reg] = q;
            }
        if (m == 0) {
            #pragma unroll
            for (int rt = 0; rt < 3; rt++)
                #pragma unroll
                for (int reg = 0; reg < 4; reg++) {
                    int row = rt * 16 + quad * 4 + reg;
                    redS[row * 4 + w] = ps[rt][reg];
                    redQ[row * 4 + w] = pq[rt][reg];
                }
        }
    }
    __syncthreads();
    if (tid < 48) {
        float s = redS[tid * 4] + redS[tid * 4 + 1] + redS[tid * 4 + 2] + redS[tid * 4 + 3];
        float q = redQ[tid * 4] + redQ[tid * 4 + 1] + redQ[tid * 4 + 2] + redQ[tid * 4 + 3];
        float mu = s * (1.f / 128.f);
        float var = q * (1.f / 128.f) - mu * mu;
        muA[tid] = mu;
        rsA[tid] = rsqrtf(var + 1e-5f);
    }
    __syncthreads();
    {
        int cb = w * 32;
        int c0 = cb + m, c1 = c0 + 16;
        float gl0 = lg[c0], gl1 = lg[c1], bl0 = lb[c0], bl1 = lb[c1];
        #pragma unroll
        for (int rt = 0; rt < 3; rt++)
            #pragma unroll
            for (int reg = 0; reg < 4; reg++) {
                int rr = rt * 16 + quad * 4 + reg;
                int gr = r0 + rr;
                if (gr < N) {
                    float mu = muA[rr], rs = rsA[rr];
                    float v0 = (y[rt][0][reg] - mu) * rs * gl0 + bl0;
                    float v1 = (y[rt][1][reg] - mu) * rs * gl1 + bl1;
                    if (FINAL) {
                        outf[(size_t)gr * 128 + c0] = v0;
                        outf[(size_t)gr * 128 + c1] = v1;
                    } else {
                        xoutb[(size_t)gr * 128 + c0] = f2us(v0);
                        xoutb[(size_t)gr * 128 + c1] = f2us(v1);
                    }
                }
            }
    }
}

extern "C" void kernel_launch(void* const* d_in, const int* in_sizes, int n_in,
                              void* d_out, int out_size, void* d_ws, size_t ws_size,
                              hipStream_t stream)
{
    const int*   eidx  = (const int*)d_in[0];
    const int*   etype = (const int*)d_in[1];
    const int*   etime = (const int*)d_in[2];
    const float* ew    = (const float*)d_in[3];
    const int*   perm  = (const int*)d_in[4];
    const float* ent   = (const float*)d_in[5];
    const float* rel   = (const float*)d_in[6];
    const float* tim   = (const float*)d_in[7];
    const float* Wi    = (const float*)d_in[8];
    const float* bi    = (const float*)d_in[9];
    const float* Wo    = (const float*)d_in[10];
    const float* bo    = (const float*)d_in[11];
    const float* Aw    = (const float*)d_in[12];
    const float* Bw    = (const float*)d_in[13];
    const float* lg    = (const float*)d_in[14];
    const float* lbp   = (const float*)d_in[15];

    char* base = (char*)d_ws;
    size_t o = 0;
    ushort_t* xbf  = (ushort_t*)(base + o); o += (size_t)N * D * 2;
    ushort_t* xb2  = (ushort_t*)(base + o); o += (size_t)N * D * 2;
    ushort_t* entb = (ushort_t*)(base + o); o += (size_t)N * D * 2;
    ushort_t* relb = (ushort_t*)(base + o); o += (size_t)200 * D * 2;
    ushort_t* timb = (ushort_t*)(base + o); o += (size_t)1000 * D * 2;
    ushort_t* WiT  = (ushort_t*)(base + o); o += (size_t)L * 256 * 128 * 2;
    ushort_t* WoT  = (ushort_t*)(base + o); o += (size_t)L * 128 * 128 * 2;
    int2*     esort  = (int2*)(base + o);   o += (size_t)E * 8;
    int*      hist   = (int*)(base + o);    o += (size_t)N * 4;
    int*      part   = (int*)(base + o);    o += (size_t)N * 4;
    int*      bsum   = (int*)(base + o);    o += 256 * 4;
    int*      cursor = (int*)(base + o);    o += (size_t)N * 4;
    int*      rowst  = (int*)(base + o);    o += (size_t)N * 4;
    int*      invp   = (int*)(base + o);    o += (size_t)N * 4;

    hipMemsetAsync(hist, 0, N * sizeof(int), stream);

    k_ctab    <<<12800, 256, 0, stream>>>(ent, rel, tim, entb, relb, timb);
    k_castw   <<<(L * 256 * 128 + L * 128 * 128 + 255) / 256, 256, 0, stream>>>(
                Wi, Wo, WiT, WoT);
    k_hist    <<<(E + 255) / 256, 256, 0, stream>>>(eidx + E, hist);
    k_scan1   <<<NB, 256, 0, stream>>>(hist, part, bsum);
    k_scan2   <<<1, 256, 0, stream>>>(bsum);
    k_finalize<<<NB, 256, 0, stream>>>(part, bsum, cursor, rowst, perm, invp);
    k_scatter <<<(E + 255) / 256, 256, 0, stream>>>(eidx, etype, etime, ew,
                                                    cursor, esort);
    k_agg     <<<(N + 3) / 4, 256, 0, stream>>>(esort, rowst, hist, invp,
                                                entb, relb, timb, xbf);

    k_layer<false><<<NBLK, 256, 0, stream>>>(
        xbf, WiT, bi, WoT, bo, Aw, Bw, lg, lbp, xb2, nullptr);
    k_layer<true><<<NBLK, 256, 0, stream>>>(
        xb2, WiT + (size_t)256 * 128, bi + 256, WoT + (size_t)128 * 128,
        bo + 128, Aw + 128, Bw + 128, lg + 128, lbp + 128,
        nullptr, (float*)d_out);
}

// Round 7
// 303.581 us; speedup vs baseline: 3.6011x; 1.0884x over previous
//
#include <hip/hip_runtime.h>
#include <hip/hip_bf16.h>

typedef unsigned short ushort_t;
typedef unsigned int   uint_t;
typedef __attribute__((ext_vector_type(8))) short bf8;
typedef __attribute__((ext_vector_type(4))) float f32x4;

constexpr int N = 50000;
constexpr int E = 600000;
constexpr int D = 128;
constexpr int L = 2;
constexpr int NB = (N + 255) / 256;

// fused layer tiling: 48 output rows/block + 16 lookback (decay 0.35^16 ~ 5e-8)
constexpr int TR   = 48;
constexpr int LOOK = 16;
constexpr int NBLK = (N + TR - 1) / TR;  // 1042
constexpr int HSTR = 136;                // hs row stride (u16), 272B = 16B-aligned

__device__ __forceinline__ float us2f(ushort_t u) {
    union { uint_t i; float f; } c; c.i = (uint_t)u << 16; return c.f;
}
__device__ __forceinline__ ushort_t f2us(float f) {
    __hip_bfloat16 b = __float2bfloat16(f);
    return *(ushort_t*)&b;
}

// ---------------------------------------------------------------------------
// Sorting passes (dst-grouped edge records)
// ---------------------------------------------------------------------------
__global__ __launch_bounds__(256) void k_hist(
    const int* __restrict__ dstp, int* __restrict__ hist)
{
    int e = blockIdx.x * 256 + threadIdx.x;
    if (e < E) atomicAdd(&hist[dstp[e]], 1);
}

__global__ __launch_bounds__(256) void k_scan1(
    const int* __restrict__ hist, int* __restrict__ part, int* __restrict__ bsum)
{
    int i = blockIdx.x * 256 + threadIdx.x;
    int v = (i < N) ? hist[i] : 0;
    int lane = threadIdx.x & 63, wv = threadIdx.x >> 6;
    int s = v;
    #pragma unroll
    for (int m = 1; m < 64; m <<= 1) {
        int t = __shfl_up(s, m, 64);
        if (lane >= m) s += t;
    }
    __shared__ int wsum[4];
    if (lane == 63) wsum[wv] = s;
    __syncthreads();
    int off = 0;
    for (int w = 0; w < wv; w++) off += wsum[w];
    if (i < N) part[i] = s - v + off;
    if (threadIdx.x == 255)
        bsum[blockIdx.x] = wsum[0] + wsum[1] + wsum[2] + wsum[3];
}

__global__ __launch_bounds__(256) void k_scan2(int* __restrict__ bsum)
{
    int i = threadIdx.x;
    int v = (i < NB) ? bsum[i] : 0;
    int lane = i & 63, wv = i >> 6;
    int s = v;
    #pragma unroll
    for (int m = 1; m < 64; m <<= 1) {
        int t = __shfl_up(s, m, 64);
        if (lane >= m) s += t;
    }
    __shared__ int wsum[4];
    if (lane == 63) wsum[wv] = s;
    __syncthreads();
    int off = 0;
    for (int w = 0; w < wv; w++) off += wsum[w];
    if (i < NB) bsum[i] = s - v + off;
}

__global__ __launch_bounds__(256) void k_finalize(
    const int* __restrict__ part, const int* __restrict__ bsum,
    int* __restrict__ cursor, int* __restrict__ rowst,
    const int* __restrict__ perm, int* __restrict__ invp)
{
    int i = blockIdx.x * 256 + threadIdx.x;
    if (i < N) {
        int b = part[i] + bsum[i >> 8];
        cursor[i] = b;
        rowst[i] = b;
        invp[perm[i]] = i;
    }
}

// packed record: x = src | (type<<16); y = time | (w_bf16<<16)
__global__ __launch_bounds__(256) void k_scatter(
    const int* __restrict__ eidx, const int* __restrict__ etype,
    const int* __restrict__ etime, const float* __restrict__ ew,
    int* __restrict__ cursor, int2* __restrict__ esort)
{
    int e = blockIdx.x * 256 + threadIdx.x;
    if (e >= E) return;
    int dst = eidx[E + e];
    int slot = atomicAdd(&cursor[dst], 1);
    int2 p;
    p.x = (eidx[e] & 0xffff) | (etype[e] << 16);
    p.y = (etime[e] & 0xffff) | ((int)f2us(ew[e]) << 16);
    esort[slot] = p;
}

// ---------------------------------------------------------------------------
// Fused cast: tables fp32->bf16 (packed), weights -> bf16 transposed
// ---------------------------------------------------------------------------
__global__ __launch_bounds__(256) void k_cast(
    const float* __restrict__ ent, const float* __restrict__ rel,
    const float* __restrict__ tim, const float* __restrict__ Wi,
    const float* __restrict__ Wo, ushort_t* __restrict__ entb,
    ushort_t* __restrict__ relb, ushort_t* __restrict__ timb,
    ushort_t* __restrict__ WiT, ushort_t* __restrict__ WoT)
{
    size_t t = (size_t)blockIdx.x * 256 + threadIdx.x;
    if (t < 3276800) {
        const float2* s; uint_t* d; size_t off;
        if (t < 3200000)      { s = (const float2*)ent; d = (uint_t*)entb; off = t; }
        else if (t < 3212800) { s = (const float2*)rel; d = (uint_t*)relb; off = t - 3200000; }
        else                  { s = (const float2*)tim; d = (uint_t*)timb; off = t - 3212800; }
        float2 v = s[off];
        d[off] = (uint_t)f2us(v.x) | ((uint_t)f2us(v.y) << 16);
    } else {
        size_t u = t - 3276800;
        if (u < (size_t)L * 256 * 128) {
            int l = u / (256 * 128), r = u % (256 * 128);
            int n = r / 128, k = r % 128;
            WiT[u] = f2us(Wi[(size_t)l * 128 * 256 + k * 256 + n]);
        } else if (u < (size_t)L * 256 * 128 + L * 128 * 128) {
            size_t v = u - (size_t)L * 256 * 128;
            int l = v / (128 * 128), r = v % (128 * 128);
            int n = r / 128, k = r % 128;
            WoT[v] = f2us(Wo[(size_t)l * 128 * 128 + k * 128 + n]);
        }
    }
}

// ---------------------------------------------------------------------------
// Aggregation: one wave per dst row; bf16 tables; packed records; unroll 4.
// ---------------------------------------------------------------------------
__global__ __launch_bounds__(256) void k_agg(
    const int2* __restrict__ esort, const int* __restrict__ rowst,
    const int* __restrict__ hist, const int* __restrict__ invp,
    const ushort_t* __restrict__ entb, const ushort_t* __restrict__ relb,
    const ushort_t* __restrict__ timb, ushort_t* __restrict__ xbf)
{
    int wv = threadIdx.x >> 6, lane = threadIdx.x & 63;
    int d = blockIdx.x * 4 + wv;
    if (d >= N) return;
    int beg = rowst[d];
    int n = hist[d];

    float s0[4] = {0.f, 0.f, 0.f, 0.f};
    float s1[4] = {0.f, 0.f, 0.f, 0.f};
    float sw[4] = {0.f, 0.f, 0.f, 0.f};

    int j = 0;
    for (; j + 3 < n; j += 4) {
        int2 rec[4];
        #pragma unroll
        for (int u = 0; u < 4; u++) rec[u] = esort[beg + j + u];
        #pragma unroll
        for (int u = 0; u < 4; u++) {
            int  sA = rec[u].x & 0xffff, tA = ((uint_t)rec[u].x) >> 16;
            int  mA = rec[u].y & 0xffff;
            float w = us2f((ushort_t)(((uint_t)rec[u].y) >> 16));
            uint_t va = *(const uint_t*)(entb + (size_t)sA * D + 2 * lane);
            uint_t vb = *(const uint_t*)(relb + (size_t)tA * D + 2 * lane);
            uint_t vc = *(const uint_t*)(timb + (size_t)mA * D + 2 * lane);
            s0[u] += (us2f(va & 0xffff) + us2f(vb & 0xffff) + us2f(vc & 0xffff)) * w;
            s1[u] += (us2f(va >> 16)    + us2f(vb >> 16)    + us2f(vc >> 16))    * w;
            sw[u] += w;
        }
    }
    for (; j < n; j++) {
        int2 p = esort[beg + j];
        int  sA = p.x & 0xffff, tA = ((uint_t)p.x) >> 16;
        int  mA = p.y & 0xffff;
        float w = us2f((ushort_t)(((uint_t)p.y) >> 16));
        uint_t va = *(const uint_t*)(entb + (size_t)sA * D + 2 * lane);
        uint_t vb = *(const uint_t*)(relb + (size_t)tA * D + 2 * lane);
        uint_t vc = *(const uint_t*)(timb + (size_t)mA * D + 2 * lane);
        s0[0] += (us2f(va & 0xffff) + us2f(vb & 0xffff) + us2f(vc & 0xffff)) * w;
        s1[0] += (us2f(va >> 16)    + us2f(vb >> 16)    + us2f(vc >> 16))    * w;
        sw[0] += w;
    }
    float a0 = (s0[0] + s0[1]) + (s0[2] + s0[3]);
    float a1 = (s1[0] + s1[1]) + (s1[2] + s1[3]);
    float wsum = (sw[0] + sw[1]) + (sw[2] + sw[3]);

    float inv = 1.0f / fmaxf(wsum, 1.0f);
    a0 *= inv; a1 *= inv;

    float ss = a0 * a0 + a1 * a1;
    #pragma unroll
    for (int m = 32; m >= 1; m >>= 1) ss += __shfl_xor(ss, m, 64);
    float sc = 1.0f / fmaxf(sqrtf(ss), 1e-12f);

    int orow = invp[d];
    uint_t out = (uint_t)f2us(a0 * sc) | ((uint_t)f2us(a1 * sc) << 16);
    *(uint_t*)(xbf + (size_t)orow * D + 2 * lane) = out;
}

// ---------------------------------------------------------------------------
// Fused mamba layer v3: scan in REGISTERS via affine-map composition.
// Wave w owns z-cols [32w,32w+32) and paired g-cols +128, so each lane holds
// z and sigmoid(g) for the same (row, dim).  Per 16-row tile: quad composes
// its 4 rows into (P,Q), 2-step shfl Blelloch over quads, apply, carry
// broadcast.  No barriers between tiles; only h goes through LDS (row-major,
// stride 136 -> ds_read_b128 in phase 3).  LDS ~15 KB.
// ---------------------------------------------------------------------------
template <bool FINAL>
__global__ __launch_bounds__(256, 4) void k_layer(
    const ushort_t* __restrict__ xin, const ushort_t* __restrict__ WiT,
    const float* __restrict__ bi, const ushort_t* __restrict__ WoT,
    const float* __restrict__ bo, const float* __restrict__ Aw,
    const float* __restrict__ Bw, const float* __restrict__ lg,
    const float* __restrict__ lb, ushort_t* __restrict__ xoutb,
    float* __restrict__ outf)
{
    __shared__ ushort_t hs[TR * HSTR];          // 13056 B
    __shared__ float redS[TR * 4], redQ[TR * 4], muA[TR], rsA[TR];

    int tid = threadIdx.x;
    int w = tid >> 6, lane = tid & 63;
    int quad = lane >> 4, m = lane & 15;
    int r0 = blockIdx.x * TR;
    int base = r0 - LOOK;

    const bf8 zero8 = {0, 0, 0, 0, 0, 0, 0, 0};
    const f32x4 zero4 = {0.f, 0.f, 0.f, 0.f};

    int cz0 = w * 32 + m;        // this lane's dim (col) pair
    int cz1 = cz0 + 16;

    float Ad0 = Aw[cz0], Bd0 = Bw[cz0];
    float Ad1 = Aw[cz1], Bd1 = Bw[cz1];
    float bz0 = bi[cz0], bz1 = bi[cz1];
    float bg0 = bi[cz0 + 128], bg1 = bi[cz1 + 128];

    // hoisted Wi B-fragments: 4 col-subtiles (z0,z1,g0,g1) x 4 kb
    bf8 Bz0[4], Bz1[4], Bg0[4], Bg1[4];
    {
        int colz0 = w * 32 + m, colz1 = colz0 + 16;
        #pragma unroll
        for (int kb = 0; kb < 4; kb++) {
            int ko = kb * 32 + quad * 8;
            Bz0[kb] = *(const bf8*)(WiT + (size_t)colz0 * 128 + ko);
            Bz1[kb] = *(const bf8*)(WiT + (size_t)colz1 * 128 + ko);
            Bg0[kb] = *(const bf8*)(WiT + (size_t)(colz0 + 128) * 128 + ko);
            Bg1[kb] = *(const bf8*)(WiT + (size_t)(colz1 + 128) * 128 + ko);
        }
    }

    // ---- phase 1+2 fused: per 16-row tile, MFMA then register scan ----
    float carry0 = 0.f, carry1 = 0.f;
    for (int rt = 0; rt < 4; rt++) {
        int gr = base + rt * 16 + m;
        bf8 a[4];
        if (gr >= 0 && gr < N) {
            #pragma unroll
            for (int kb = 0; kb < 4; kb++)
                a[kb] = *(const bf8*)(xin + (size_t)gr * 128 + kb * 32 + quad * 8);
        } else {
            #pragma unroll
            for (int kb = 0; kb < 4; kb++) a[kb] = zero8;
        }
        f32x4 az0 = zero4, az1 = zero4, ag0 = zero4, ag1 = zero4;
        #pragma unroll
        for (int kb = 0; kb < 4; kb++) {
            az0 = __builtin_amdgcn_mfma_f32_16x16x32_bf16(a[kb], Bz0[kb], az0, 0, 0, 0);
            az1 = __builtin_amdgcn_mfma_f32_16x16x32_bf16(a[kb], Bz1[kb], az1, 0, 0, 0);
            ag0 = __builtin_amdgcn_mfma_f32_16x16x32_bf16(a[kb], Bg0[kb], ag0, 0, 0, 0);
            ag1 = __builtin_amdgcn_mfma_f32_16x16x32_bf16(a[kb], Bg1[kb], ag1, 0, 0, 0);
        }
        // lane holds rows quad*4+reg of cols cz0/cz1: z and pre-sigmoid g.
        // Overwrite az*/ag* with per-row affine coeffs (a,b).
        float P0 = 1.f, Q0 = 0.f, P1 = 1.f, Q1 = 0.f;
        #pragma unroll
        for (int reg = 0; reg < 4; reg++) {
            int grr = base + rt * 16 + quad * 4 + reg;
            bool ok = (grr >= 0) && (grr < N);
            float z0 = az0[reg] + bz0, z1 = az1[reg] + bz1;
            float g0 = 1.f / (1.f + __expf(-(ag0[reg] + bg0)));
            float g1 = 1.f / (1.f + __expf(-(ag1[reg] + bg1)));
            float ca0 = ok ? g0 * Ad0 : 0.f, cb0 = ok ? Bd0 * z0 : 0.f;
            float ca1 = ok ? g1 * Ad1 : 0.f, cb1 = ok ? Bd1 * z1 : 0.f;
            az0[reg] = ca0; ag0[reg] = cb0;
            az1[reg] = ca1; ag1[reg] = cb1;
            P0 = ca0 * P0; Q0 = ca0 * Q0 + cb0;
            P1 = ca1 * P1; Q1 = ca1 * Q1 + cb1;
        }
        // inclusive Blelloch over quads (lanes differ by 16)
        float Pp, Qp;
        Pp = __shfl_up(P0, 16, 64); Qp = __shfl_up(Q0, 16, 64);
        if (quad >= 1) { Q0 = P0 * Qp + Q0; P0 = P0 * Pp; }
        Pp = __shfl_up(P1, 16, 64); Qp = __shfl_up(Q1, 16, 64);
        if (quad >= 1) { Q1 = P1 * Qp + Q1; P1 = P1 * Pp; }
        Pp = __shfl_up(P0, 32, 64); Qp = __shfl_up(Q0, 32, 64);
        if (quad >= 2) { Q0 = P0 * Qp + Q0; P0 = P0 * Pp; }
        Pp = __shfl_up(P1, 32, 64); Qp = __shfl_up(Q1, 32, 64);
        if (quad >= 2) { Q1 = P1 * Qp + Q1; P1 = P1 * Pp; }
        // exclusive prefix (shift by one quad)
        float Pe0 = __shfl_up(P0, 16, 64), Qe0 = __shfl_up(Q0, 16, 64);
        float Pe1 = __shfl_up(P1, 16, 64), Qe1 = __shfl_up(Q1, 16, 64);
        if (quad == 0) { Pe0 = 1.f; Qe0 = 0.f; Pe1 = 1.f; Qe1 = 0.f; }
        float h0 = Pe0 * carry0 + Qe0;
        float h1 = Pe1 * carry1 + Qe1;
        // carry update from quad3's inclusive map
        float Pc0 = __shfl(P0, m + 48, 64), Qc0 = __shfl(Q0, m + 48, 64);
        float Pc1 = __shfl(P1, m + 48, 64), Qc1 = __shfl(Q1, m + 48, 64);
        carry0 = Pc0 * carry0 + Qc0;
        carry1 = Pc1 * carry1 + Qc1;
        // apply per row + store h (output rows only)
        #pragma unroll
        for (int reg = 0; reg < 4; reg++) {
            h0 = az0[reg] * h0 + ag0[reg];
            h1 = az1[reg] * h1 + ag1[reg];
            if (rt >= 1) {
                int lrow = (rt - 1) * 16 + quad * 4 + reg;
                hs[lrow * HSTR + cz0] = f2us(h0);
                hs[lrow * HSTR + cz1] = f2us(h1);
            }
        }
    }
    __syncthreads();

    // ---- phase 3: y = x + h @ Wo + bo  (y stays in registers) ----
    float y[3][2][4];
    {
        int c0 = w * 32 + m, c1 = c0 + 16;
        float bias0 = bo[c0], bias1 = bo[c1];
        bf8 b0[4], b1[4];
        #pragma unroll
        for (int kb = 0; kb < 4; kb++) {
            int ko = kb * 32 + quad * 8;
            b0[kb] = *(const bf8*)(WoT + (size_t)c0 * 128 + ko);
            b1[kb] = *(const bf8*)(WoT + (size_t)c1 * 128 + ko);
        }
        #pragma unroll
        for (int rt = 0; rt < 3; rt++) {
            bf8 a[4];
            #pragma unroll
            for (int kb = 0; kb < 4; kb++)
                a[kb] = *(const bf8*)(hs + (rt * 16 + m) * HSTR + kb * 32 + quad * 8);
            f32x4 acc0 = zero4, acc1 = zero4;
            #pragma unroll
            for (int kb = 0; kb < 4; kb++) {
                acc0 = __builtin_amdgcn_mfma_f32_16x16x32_bf16(a[kb], b0[kb], acc0, 0, 0, 0);
                acc1 = __builtin_amdgcn_mfma_f32_16x16x32_bf16(a[kb], b1[kb], acc1, 0, 0, 0);
            }
            #pragma unroll
            for (int reg = 0; reg < 4; reg++) {
                int gr = r0 + rt * 16 + quad * 4 + reg;
                float r0v = 0.f, r1v = 0.f;
                if (gr < N) {
                    r0v = us2f(xin[(size_t)gr * 128 + c0]);
                    r1v = us2f(xin[(size_t)gr * 128 + c1]);
                }
                y[rt][0][reg] = acc0[reg] + bias0 + r0v;
                y[rt][1][reg] = acc1[reg] + bias1 + r1v;
            }
        }
    }

    // ---- phase 4: LayerNorm (register shuffle + small LDS combine) ----
    {
        #pragma unroll
        for (int rt = 0; rt < 3; rt++)
            #pragma unroll
            for (int reg = 0; reg < 4; reg++) {
                float v0 = y[rt][0][reg], v1 = y[rt][1][reg];
                float s = v0 + v1, q = v0 * v0 + v1 * v1;
                #pragma unroll
                for (int mk = 1; mk <= 8; mk <<= 1) {
                    s += __shfl_xor(s, mk, 64);
                    q += __shfl_xor(q, mk, 64);
                }
                if (m == 0) {
                    int row = rt * 16 + quad * 4 + reg;
                    redS[row * 4 + w] = s;
                    redQ[row * 4 + w] = q;
                }
            }
    }
    __syncthreads();
    if (tid < TR) {
        float s = redS[tid * 4] + redS[tid * 4 + 1] + redS[tid * 4 + 2] + redS[tid * 4 + 3];
        float q = redQ[tid * 4] + redQ[tid * 4 + 1] + redQ[tid * 4 + 2] + redQ[tid * 4 + 3];
        float mu = s * (1.f / 128.f);
        float var = q * (1.f / 128.f) - mu * mu;
        muA[tid] = mu;
        rsA[tid] = rsqrtf(var + 1e-5f);
    }
    __syncthreads();
    {
        int c0 = w * 32 + m, c1 = c0 + 16;
        float gl0 = lg[c0], gl1 = lg[c1], bl0 = lb[c0], bl1 = lb[c1];
        #pragma unroll
        for (int rt = 0; rt < 3; rt++)
            #pragma unroll
            for (int reg = 0; reg < 4; reg++) {
                int rr = rt * 16 + quad * 4 + reg;
                int gr = r0 + rr;
                if (gr < N) {
                    float mu = muA[rr], rs = rsA[rr];
                    float v0 = (y[rt][0][reg] - mu) * rs * gl0 + bl0;
                    float v1 = (y[rt][1][reg] - mu) * rs * gl1 + bl1;
                    if (FINAL) {
                        outf[(size_t)gr * 128 + c0] = v0;
                        outf[(size_t)gr * 128 + c1] = v1;
                    } else {
                        xoutb[(size_t)gr * 128 + c0] = f2us(v0);
                        xoutb[(size_t)gr * 128 + c1] = f2us(v1);
                    }
                }
            }
    }
}

extern "C" void kernel_launch(void* const* d_in, const int* in_sizes, int n_in,
                              void* d_out, int out_size, void* d_ws, size_t ws_size,
                              hipStream_t stream)
{
    const int*   eidx  = (const int*)d_in[0];
    const int*   etype = (const int*)d_in[1];
    const int*   etime = (const int*)d_in[2];
    const float* ew    = (const float*)d_in[3];
    const int*   perm  = (const int*)d_in[4];
    const float* ent   = (const float*)d_in[5];
    const float* rel   = (const float*)d_in[6];
    const float* tim   = (const float*)d_in[7];
    const float* Wi    = (const float*)d_in[8];
    const float* bi    = (const float*)d_in[9];
    const float* Wo    = (const float*)d_in[10];
    const float* bo    = (const float*)d_in[11];
    const float* Aw    = (const float*)d_in[12];
    const float* Bw    = (const float*)d_in[13];
    const float* lg    = (const float*)d_in[14];
    const float* lbp   = (const float*)d_in[15];

    char* base = (char*)d_ws;
    size_t o = 0;
    ushort_t* xbf  = (ushort_t*)(base + o); o += (size_t)N * D * 2;
    ushort_t* xb2  = (ushort_t*)(base + o); o += (size_t)N * D * 2;
    ushort_t* entb = (ushort_t*)(base + o); o += (size_t)N * D * 2;
    ushort_t* relb = (ushort_t*)(base + o); o += (size_t)200 * D * 2;
    ushort_t* timb = (ushort_t*)(base + o); o += (size_t)1000 * D * 2;
    ushort_t* WiT  = (ushort_t*)(base + o); o += (size_t)L * 256 * 128 * 2;
    ushort_t* WoT  = (ushort_t*)(base + o); o += (size_t)L * 128 * 128 * 2;
    int2*     esort  = (int2*)(base + o);   o += (size_t)E * 8;
    int*      hist   = (int*)(base + o);    o += (size_t)N * 4;
    int*      part   = (int*)(base + o);    o += (size_t)N * 4;
    int*      bsum   = (int*)(base + o);    o += 256 * 4;
    int*      cursor = (int*)(base + o);    o += (size_t)N * 4;
    int*      rowst  = (int*)(base + o);    o += (size_t)N * 4;
    int*      invp   = (int*)(base + o);    o += (size_t)N * 4;

    hipMemsetAsync(hist, 0, N * sizeof(int), stream);

    k_cast    <<<13185, 256, 0, stream>>>(ent, rel, tim, Wi, Wo,
                                          entb, relb, timb, WiT, WoT);
    k_hist    <<<(E + 255) / 256, 256, 0, stream>>>(eidx + E, hist);
    k_scan1   <<<NB, 256, 0, stream>>>(hist, part, bsum);
    k_scan2   <<<1, 256, 0, stream>>>(bsum);
    k_finalize<<<NB, 256, 0, stream>>>(part, bsum, cursor, rowst, perm, invp);
    k_scatter <<<(E + 255) / 256, 256, 0, stream>>>(eidx, etype, etime, ew,
                                                    cursor, esort);
    k_agg     <<<(N + 3) / 4, 256, 0, stream>>>(esort, rowst, hist, invp,
                                                entb, relb, timb, xbf);

    k_layer<false><<<NBLK, 256, 0, stream>>>(
        xbf, WiT, bi, WoT, bo, Aw, Bw, lg, lbp, xb2, nullptr);
    k_layer<true><<<NBLK, 256, 0, stream>>>(
        xb2, WiT + (size_t)256 * 128, bi + 256, WoT + (size_t)128 * 128,
        bo + 128, Aw + 128, Bw + 128, lg + 128, lbp + 128,
        nullptr, (float*)d_out);
}